// Round 9
// baseline (568.769 us; speedup 1.0000x reference)
//
#include <hip/hip_runtime.h>
#include <hip/hip_bf16.h>
#include <math.h>

#define LLY 3
#define BB 16
#define NNQ 256
#define DD 768
#define MMP 2048
#define HH 128
#define MD 64
#define IMGSZ 240
#define LBTOT (LLY*BB)

// ---------------- workspace layout (floats) ----------------
#define OFF_INVQ 0
#define OFF_INVP (OFF_INVQ + LLY*BB*NNQ)
#define OFF_CMAP (OFF_INVP + LLY*BB*MMP)
#define OFF_BNSH (OFF_CMAP + LLY*BB*DD*NNQ)
#define OFF_X1   (OFF_BNSH + 2*LLY*DD)
#define OFF_BN1  (OFF_X1 + LLY*BB*HH*256)
#define OFF_T1   (OFF_BN1 + 2*LLY*HH)
#define OFF_X2   (OFF_T1 + LLY*BB*HH*1024)
#define OFF_BN2  (OFF_X2 + LLY*BB*MD*1024)
#define OFF_T2   (OFF_BN2 + 2*LLY*MD)
#define OFF_RAW3 (OFF_T2 + LLY*BB*MD*4096)
#define WS_FLOATS (OFF_RAW3 + LLY*BB*2*4096)
#define T1BSH (LBTOT*1024*HH)      // shorts
#define SQH   (LBTOT*NNQ*DD)       // shorts per q-split plane
#define OFF_C1P (OFF_T2 + 4718592)
#define OFF_C2P (OFF_T2 + 3256320)
#define OFF_PGL OFF_X1

// ---------------- output layout (floats) ----------------
#define O_RES 0
#define O_PSC (O_RES + LLY*BB*NNQ)
#define O_PLG (O_PSC + LLY*BB*NNQ)
#define O_GLG (O_PLG + LLY*BB*NNQ)
#define O_LOC (O_GLG + LLY*BB)
#define O_PW  (O_LOC + LLY*BB*2*IMGSZ*IMGSZ)
#define O_IDX (O_PW + LLY*2)
#define O_ALN (O_IDX + LLY*BB*NNQ)

typedef __attribute__((ext_vector_type(8))) short bf16x8;
typedef __attribute__((ext_vector_type(4))) float f32x4;

__device__ __forceinline__ unsigned short f2bf(float f) {
    __hip_bfloat16 h = __float2bfloat16(f);
    unsigned short u;
    __builtin_memcpy(&u, &h, sizeof(u));
    return u;
}
__device__ __forceinline__ float bf2f(unsigned short h) {
    return __uint_as_float(((unsigned int)h) << 16);
}

__device__ __forceinline__ float blockReduceSum(float v, float* sm) {
    for (int o = 32; o; o >>= 1) v += __shfl_down(v, o, 64);
    __syncthreads();
    if ((threadIdx.x & 63) == 0) sm[threadIdx.x >> 6] = v;
    __syncthreads();
    return sm[0] + sm[1] + sm[2] + sm[3];
}

// ------- fused: query row L2-norm + normalized bf16 hi/lo split (into T2 region) -----
__global__ __launch_bounds__(192) void knormq(const float* __restrict__ query,
                                              float* __restrict__ ws) {
    __shared__ float sm[3];
    int row = blockIdx.x;
    int t = threadIdx.x;
    float4 v = *(const float4*)(query + (size_t)row * DD + t * 4);
    float ss = v.x * v.x + v.y * v.y + v.z * v.z + v.w * v.w;
    for (int o = 32; o; o >>= 1) ss += __shfl_down(ss, o, 64);
    if ((t & 63) == 0) sm[t >> 6] = ss;
    __syncthreads();
    ss = sm[0] + sm[1] + sm[2];
    float iv = 1.0f / fmaxf(sqrtf(ss), 1e-12f);
    if (t == 0) ws[OFF_INVQ + row] = iv;
    unsigned short* qh = (unsigned short*)(ws + OFF_T2);
    unsigned short* ql = qh + SQH;
    float e[4] = {v.x * iv, v.y * iv, v.z * iv, v.w * iv};
    unsigned int hp[2], lp[2];
    #pragma unroll
    for (int j = 0; j < 2; j++) {
        unsigned short h0 = f2bf(e[2*j]), h1 = f2bf(e[2*j+1]);
        unsigned short l0 = f2bf(e[2*j] - bf2f(h0)), l1 = f2bf(e[2*j+1] - bf2f(h1));
        hp[j] = (unsigned int)h0 | ((unsigned int)h1 << 16);
        lp[j] = (unsigned int)l0 | ((unsigned int)l1 << 16);
    }
    *(uint2*)(qh + (size_t)row * DD + t * 4) = make_uint2(hp[0], hp[1]);
    *(uint2*)(ql + (size_t)row * DD + t * 4) = make_uint2(lp[0], lp[1]);
}

// ---- sim GEMM: 128p x 256q block, 8 waves of 64x64, fused p-norm, 36-short stride ---
__global__ __launch_bounds__(512) void ksimm(const float* __restrict__ prompt, float* __restrict__ ws) {
    __shared__ __align__(16) unsigned short Ah[128][36];
    __shared__ __align__(16) unsigned short Al[128][36];
    __shared__ __align__(16) unsigned short Bh[256][36];
    __shared__ __align__(16) unsigned short Bl[256][36];
    __shared__ float invL[128];
    int bid = blockIdx.x;
    int mt = bid & 15;
    int lb = bid >> 4;
    int t = threadIdx.x;
    int lane = t & 63, wave = t >> 6;
    int wm = wave >> 2, wn = wave & 3;
    int fr = lane & 15, fq = lane >> 4;
    const unsigned short* qh = (const unsigned short*)(ws + OFF_T2);
    const unsigned short* ql = qh + SQH;
    const float* pbase = prompt + (size_t)lb * MMP * DD + (size_t)(mt * 128) * DD;

    float ssq[2] = {0.f, 0.f};

    f32x4 acc[4][4];
    #pragma unroll
    for (int mi = 0; mi < 4; mi++)
        #pragma unroll
        for (int ni = 0; ni < 4; ni++) acc[mi][ni] = (f32x4){0.f, 0.f, 0.f, 0.f};

    for (int kc = 0; kc < DD; kc += 32) {
        __syncthreads();
        #pragma unroll
        for (int i = 0; i < 2; i++) {          // stage P: 128 x 32 f32 -> hi/lo (+ssq)
            int f = t + i * 512;
            int row = f >> 3, c4 = f & 7;
            float4 v = *(const float4*)(pbase + (size_t)row * DD + kc + c4 * 4);
            ssq[i] += v.x * v.x + v.y * v.y + v.z * v.z + v.w * v.w;
            unsigned short h0 = f2bf(v.x), h1 = f2bf(v.y), h2 = f2bf(v.z), h3 = f2bf(v.w);
            unsigned short l0 = f2bf(v.x - bf2f(h0)), l1 = f2bf(v.y - bf2f(h1));
            unsigned short l2 = f2bf(v.z - bf2f(h2)), l3 = f2bf(v.w - bf2f(h3));
            uint2 hp = make_uint2((unsigned int)h0 | ((unsigned int)h1 << 16),
                                  (unsigned int)h2 | ((unsigned int)h3 << 16));
            uint2 lp = make_uint2((unsigned int)l0 | ((unsigned int)l1 << 16),
                                  (unsigned int)l2 | ((unsigned int)l3 << 16));
            *(uint2*)&Ah[row][c4 * 4] = hp;
            *(uint2*)&Al[row][c4 * 4] = lp;
        }
        #pragma unroll
        for (int i = 0; i < 2; i++) {          // stage Q: 256 x 32 bf16 hi/lo
            int f = t + i * 512;
            int row = f >> 2, sg = f & 3;
            size_t go = (size_t)(lb * NNQ + row) * DD + kc + sg * 8;
            *(uint4*)&Bh[row][sg * 8] = *(const uint4*)(qh + go);
            *(uint4*)&Bl[row][sg * 8] = *(const uint4*)(ql + go);
        }
        __syncthreads();
        bf16x8 ah[4], al4[4], bh[4], bl4[4];
        #pragma unroll
        for (int mi = 0; mi < 4; mi++) {
            ah[mi]  = *(const bf16x8*)&Ah[wm * 64 + mi * 16 + fr][fq * 8];
            al4[mi] = *(const bf16x8*)&Al[wm * 64 + mi * 16 + fr][fq * 8];
        }
        #pragma unroll
        for (int ni = 0; ni < 4; ni++) {
            bh[ni]  = *(const bf16x8*)&Bh[wn * 64 + ni * 16 + fr][fq * 8];
            bl4[ni] = *(const bf16x8*)&Bl[wn * 64 + ni * 16 + fr][fq * 8];
        }
        #pragma unroll
        for (int mi = 0; mi < 4; mi++)
            #pragma unroll
            for (int ni = 0; ni < 4; ni++) {
                acc[mi][ni] = __builtin_amdgcn_mfma_f32_16x16x32_bf16(ah[mi],  bh[ni],  acc[mi][ni], 0, 0, 0);
                acc[mi][ni] = __builtin_amdgcn_mfma_f32_16x16x32_bf16(ah[mi],  bl4[ni], acc[mi][ni], 0, 0, 0);
                acc[mi][ni] = __builtin_amdgcn_mfma_f32_16x16x32_bf16(al4[mi], bh[ni],  acc[mi][ni], 0, 0, 0);
            }
    }
    // prompt norms: reduce ssq across the 8 staging lanes per row
    #pragma unroll
    for (int i = 0; i < 2; i++) {
        float s = ssq[i];
        s += __shfl_xor(s, 1, 64);
        s += __shfl_xor(s, 2, 64);
        s += __shfl_xor(s, 4, 64);
        if ((t & 7) == 0) {
            int row = (t >> 3) + 64 * i;
            float iv = 1.0f / fmaxf(sqrtf(s), 1e-12f);
            invL[row] = iv;
            ws[OFF_INVP + lb * MMP + mt * 128 + row] = iv;
        }
    }
    __syncthreads();
    // fold invp + per-wave argmax over 64 prompts (ascending m within wave)
    float* bestv = ws + OFF_X1;
    float* besti = ws + OFF_X1 + (size_t)LBTOT * NNQ * 32;
    #pragma unroll
    for (int ni = 0; ni < 4; ni++) {
        float bv = -1e30f; int bi = 0;
        #pragma unroll
        for (int mi = 0; mi < 4; mi++)
            #pragma unroll
            for (int rr = 0; rr < 4; rr++) {
                int lm = wm * 64 + mi * 16 + fq * 4 + rr;
                float s = acc[mi][ni][rr] * invL[lm];
                int m = mt * 128 + lm;
                if (s > bv) { bv = s; bi = m; }
            }
        #pragma unroll
        for (int o = 16; o <= 32; o <<= 1) {
            float ov = __shfl_xor(bv, o, 64);
            int oi = __shfl_xor(bi, o, 64);
            if (ov > bv || (ov == bv && oi < bi)) { bv = ov; bi = oi; }
        }
        if (fq == 0) {
            int q = wn * 64 + ni * 16 + fr;
            size_t slot = (size_t)(lb * NNQ + q) * 32 + wm * 16 + mt;
            bestv[slot] = bv;
            besti[slot] = (float)bi;
        }
    }
}

// ---------------- argmax finalize + residual/idx/aligned/ctx(cmap) ----------------
__global__ __launch_bounds__(256) void kpost(const float* __restrict__ query,
                                             const float* __restrict__ prompt,
                                             float* __restrict__ ws,
                                             float* __restrict__ out) {
    __shared__ float red_v[16];
    __shared__ int   red_i[16];
    int bid = blockIdx.x;
    int nt = bid & 15;
    int lb = bid >> 4;
    int t = threadIdx.x;
    const float* bestv = ws + OFF_X1;
    const float* besti = ws + OFF_X1 + (size_t)LBTOT * NNQ * 32;
    if (t < 16) {
        int q = nt * 16 + t;
        const float* bv = bestv + (size_t)(lb * NNQ + q) * 32;
        const float* bi = besti + (size_t)(lb * NNQ + q) * 32;
        float best = -1e30f; int bidx2 = 0;
        for (int mtt = 0; mtt < 16; mtt++)
            #pragma unroll
            for (int wm = 0; wm < 2; wm++) {   // (mt,wm) lexicographic = ascending m
                float v = bv[wm * 16 + mtt];
                if (v > best) { best = v; bidx2 = (int)bi[wm * 16 + mtt]; }
            }
        red_v[t] = best; red_i[t] = bidx2;
        out[O_RES + lb * NNQ + q] = 0.5f * (1.0f - best);
        out[O_IDX + lb * NNQ + q] = (float)bidx2;
    }
    __syncthreads();
    const float* qbase = query + (size_t)(lb * NNQ + nt * 16) * DD;
    const float* pbase = prompt + (size_t)lb * MMP * DD;
    const float* invq = ws + OFF_INVQ + lb * NNQ + nt * 16;
    const float* invp = ws + OFF_INVP + lb * MMP;
    int c = t & 15;
    int nn = t >> 4;
    int gn = nt * 16 + nn;
    int midx = red_i[nn];
    float ip = invp[midx];
    float iq = invq[nn];
    const float* prow = pbase + (size_t)midx * DD;
    const float* qrow = qbase + (size_t)nn * DD;
    float* cm = ws + OFF_CMAP + (size_t)lb * DD * NNQ;
    float* aln = out + O_ALN + (size_t)(lb * NNQ + gn) * DD;
    for (int jj = 0; jj < DD / 16; jj++) {
        int d = c + jj * 16;
        float pvr = prow[d];
        float qv = qrow[d] * iq;
        float av = pvr * ip;
        float cx = qv + fabsf(qv - av);
        aln[d] = pvr;
        cm[(size_t)d * NNQ + gn] = cx;
    }
}

// ---------------- BN batch stats (per l,c over B x SP), biased var ----------------
__global__ __launch_bounds__(256) void kbnstats(const float* __restrict__ x, int C, int SP,
                                                const float* __restrict__ g,
                                                const float* __restrict__ b,
                                                float* __restrict__ outSB) {
    __shared__ float sm[4];
    int bid = blockIdx.x;
    int c = bid % C;
    int l = bid / C;
    int t = threadIdx.x;
    float s = 0.f, sq = 0.f;
    for (int bb2 = 0; bb2 < BB; ++bb2) {
        const float* p = x + ((size_t)(l * BB + bb2) * C + c) * SP;
        for (int i = t; i < SP; i += 256) { float v = p[i]; s += v; sq += v * v; }
    }
    s = blockReduceSum(s, sm);
    sq = blockReduceSum(sq, sm);
    if (t == 0) {
        float inv = 1.0f / (float)(BB * SP);
        float m = s * inv;
        float var = sq * inv - m * m;
        float sc = g[l * C + c] * rsqrtf(var + 1e-5f);
        float bo = b[l * C + c] - m * sc;
        outSB[l * C + c] = sc;
        outSB[LLY * C + l * C + c] = bo;
    }
}

// ---------------- weight repack: lw1 f32 [l][co][ci][9] -> bf16 [l][tap][co][ci] -----
__global__ __launch_bounds__(256) void kw1cvt(const float* __restrict__ lw1, float* __restrict__ ws) {
    unsigned short* w1B = (unsigned short*)(ws + OFF_X2);
    int bid = blockIdx.x;
    int l = bid / HH, co = bid % HH;
    int t = threadIdx.x;
    for (int c0 = 0; c0 < DD; c0 += 256) {
        int ci = c0 + t;
        const float* src = lw1 + ((size_t)(l * HH + co) * DD + ci) * 9;
        #pragma unroll
        for (int tap = 0; tap < 9; tap++) {
            w1B[((size_t)((l * 9 + tap) * HH + co)) * DD + ci] = f2bf(src[tap]);
        }
    }
}

// ---------------- BN-fold + transpose: cmap f32 [lb][ci][n] -> bf16 cmT [lb][n][ci] --
__global__ __launch_bounds__(256) void kbn1cvt(float* __restrict__ ws) {
    __shared__ float Ld[64][65];
    unsigned short* cmT = (unsigned short*)(ws + OFF_T2);
    int bid = blockIdx.x;
    int nt = bid & 3;
    int r = bid >> 2;
    int ct = r % 12;
    int lb = r / 12;
    int l = lb >> 4;
    int t = threadIdx.x;
    const float* cmap = ws + OFF_CMAP + (size_t)lb * DD * NNQ;
    const float* bns = ws + OFF_BNSH + l * DD;
    const float* bnb = ws + OFF_BNSH + LLY * DD + l * DD;
    #pragma unroll
    for (int i = 0; i < 4; i++) {
        int f = t + i * 256;
        int row = f >> 4, c4 = f & 15;
        int ci = ct * 64 + row;
        float4 v = *(const float4*)(cmap + (size_t)ci * NNQ + nt * 64 + c4 * 4);
        float s = bns[ci], bo = bnb[ci];
        Ld[row][c4*4+0] = v.x * s + bo; Ld[row][c4*4+1] = v.y * s + bo;
        Ld[row][c4*4+2] = v.z * s + bo; Ld[row][c4*4+3] = v.w * s + bo;
    }
    __syncthreads();
    #pragma unroll
    for (int i = 0; i < 2; i++) {
        int f = t + i * 256;
        int row = f >> 3, seg = f & 7;
        unsigned int pk[4];
        #pragma unroll
        for (int e = 0; e < 4; e++) {
            unsigned int lo = f2bf(Ld[seg * 8 + 2 * e][row]);
            unsigned int hi = f2bf(Ld[seg * 8 + 2 * e + 1][row]);
            pk[e] = lo | (hi << 16);
        }
        uint4 o = make_uint4(pk[0], pk[1], pk[2], pk[3]);
        *(uint4*)(cmT + ((size_t)(lb * NNQ + nt * 64 + row)) * DD + ct * 64 + seg * 8) = o;
    }
}

// ------- conv1 MFMA, split-K x6: 128co x 128n per block, 18 of 108 kc-chunks each ----
__global__ __launch_bounds__(256) void kconv1m(float* __restrict__ ws) {
    __shared__ __align__(16) unsigned short Ab[128][72];
    __shared__ __align__(16) unsigned short Bb[128][72];
    int bid = blockIdx.x;
    int s = bid % 6;
    int ntile = (bid / 6) & 1;
    int lb = bid / 12;
    int l = lb >> 4;
    int t = threadIdx.x;
    int lane = t & 63;
    int wave = t >> 6;
    int wr = wave >> 1, wc = wave & 1;
    int fr = lane & 15, fq = lane >> 4;
    const unsigned short* w1B = (const unsigned short*)(ws + OFF_X2);
    const unsigned short* cmT = (const unsigned short*)(ws + OFF_T2);

    f32x4 acc[4][4];
    #pragma unroll
    for (int mi = 0; mi < 4; mi++)
        #pragma unroll
        for (int ni = 0; ni < 4; ni++) acc[mi][ni] = (f32x4){0.f, 0.f, 0.f, 0.f};

    for (int g = s * 18; g < s * 18 + 18; ++g) {
        int tap = g / 12;
        int kc = (g % 12) * 64;
        int dy = tap / 3 - 1, dx = tap % 3 - 1;
        const unsigned short* wpl = w1B + (size_t)((l * 9 + tap) * HH) * DD;
        __syncthreads();
        #pragma unroll
        for (int i = 0; i < 4; i++) {
            int f = t + i * 256;
            int row = f >> 3, seg = f & 7;
            uint4 v = *(const uint4*)(wpl + (size_t)row * DD + kc + seg * 8);
            *(uint4*)&Ab[row][seg * 8] = v;
        }
        #pragma unroll
        for (int i = 0; i < 4; i++) {
            int f = t + i * 256;
            int row = f >> 3, seg = f & 7;
            int n = ntile * 128 + row;
            int y = (n >> 4) + dy, x = (n & 15) + dx;
            bool ok = ((unsigned)y < 16u) && ((unsigned)x < 16u);
            uint4 v = make_uint4(0u, 0u, 0u, 0u);
            if (ok) v = *(const uint4*)(cmT + ((size_t)(lb * NNQ + y * 16 + x)) * DD + kc + seg * 8);
            *(uint4*)&Bb[row][seg * 8] = v;
        }
        __syncthreads();
        #pragma unroll
        for (int kk = 0; kk < 64; kk += 32) {
            bf16x8 af[4], bfv[4];
            #pragma unroll
            for (int mi = 0; mi < 4; mi++)
                af[mi] = *(const bf16x8*)&Ab[wr * 64 + mi * 16 + fr][kk + fq * 8];
            #pragma unroll
            for (int ni = 0; ni < 4; ni++)
                bfv[ni] = *(const bf16x8*)&Bb[wc * 64 + ni * 16 + fr][kk + fq * 8];
            #pragma unroll
            for (int mi = 0; mi < 4; mi++)
                #pragma unroll
                for (int ni = 0; ni < 4; ni++)
                    acc[mi][ni] = __builtin_amdgcn_mfma_f32_16x16x32_bf16(af[mi], bfv[ni], acc[mi][ni], 0, 0, 0);
        }
    }
    float* dst = (s == 5) ? (ws + OFF_X1 + (size_t)lb * HH * 256)
                          : (ws + OFF_C1P + (size_t)(s * LBTOT + lb) * (HH * 256));
    #pragma unroll
    for (int mi = 0; mi < 4; mi++) {
        #pragma unroll
        for (int ni = 0; ni < 4; ni++) {
            int gn = ntile * 128 + wc * 64 + ni * 16 + fr;
            #pragma unroll
            for (int rr = 0; rr < 4; rr++) {
                int co = wr * 64 + mi * 16 + fq * 4 + rr;
                dst[(size_t)co * 256 + gn] = acc[mi][ni][rr];
            }
        }
    }
}

// ---------------- reduce conv1 partials into X1 ----------------
__global__ __launch_bounds__(256) void kc1red(float* __restrict__ ws) {
    size_t i = ((size_t)blockIdx.x * 256 + threadIdx.x) * 8;
    float4 a0 = *(float4*)(ws + OFF_X1 + i);
    float4 a1 = *(float4*)(ws + OFF_X1 + i + 4);
    #pragma unroll
    for (int s = 0; s < 5; s++) {
        const float* p = ws + OFF_C1P + (size_t)s * (LBTOT * HH * 256) + i;
        float4 b0 = *(const float4*)p;
        float4 b1 = *(const float4*)(p + 4);
        a0.x += b0.x; a0.y += b0.y; a0.z += b0.z; a0.w += b0.w;
        a1.x += b1.x; a1.y += b1.y; a1.z += b1.z; a1.w += b1.w;
    }
    *(float4*)(ws + OFF_X1 + i) = a0;
    *(float4*)(ws + OFF_X1 + i + 4) = a1;
}

// ---------------- convT 2x2 s2 (generic), input = relu(bn(xin)) ----------------
__global__ __launch_bounds__(256) void kconvT(const float* __restrict__ wt,
                                              const float* __restrict__ bt,
                                              const float* __restrict__ xin,
                                              const float* __restrict__ sbsb,
                                              float* __restrict__ xout,
                                              int CI, int CO, int gsh, int nTiles, int oTiles) {
    __shared__ __align__(16) float In[16][256];
    __shared__ __align__(16) float Wc[16][32];
    int bid = blockIdx.x;
    int ntile = bid % nTiles;
    int rem = bid / nTiles;
    int pq = rem & 3; rem >>= 2;
    int ot = rem % oTiles;
    int lb = rem / oTiles;
    int l = lb >> 4;
    int SPIN = 1 << (2 * gsh);
    int t = threadIdx.x, tc = t >> 5, tn = t & 31;
    const float* sc = sbsb + l * CI;
    const float* bo = sbsb + LLY * CI + l * CI;
    float acc[4][8] = {};

    for (int cc = 0; cc < CI; cc += 16) {
        __syncthreads();
        #pragma unroll
        for (int i = 0; i < 4; i++) {
            int fid = t + i * 256;
            int r = fid >> 6, c4 = fid & 63;
            int ci = cc + r;
            float4 v = *(const float4*)(xin + (size_t)(lb * CI + ci) * SPIN + ntile * 256 + c4 * 4);
            float s = sc[ci], bb_ = bo[ci];
            v.x = fmaxf(v.x * s + bb_, 0.f); v.y = fmaxf(v.y * s + bb_, 0.f);
            v.z = fmaxf(v.z * s + bb_, 0.f); v.w = fmaxf(v.w * s + bb_, 0.f);
            *(float4*)&In[r][c4 * 4] = v;
        }
        #pragma unroll
        for (int i = 0; i < 2; i++) {
            int idx = t + i * 256;
            int c_l = idx >> 5, o_l = idx & 31;
            Wc[c_l][o_l] = wt[((size_t)(l * CI + cc + c_l) * CO + ot * 32 + o_l) * 4 + pq];
        }
        __syncthreads();
        #pragma unroll
        for (int ci = 0; ci < 16; ci++) {
            float4 w4 = *(const float4*)&Wc[ci][tc * 4];
            #pragma unroll
            for (int j = 0; j < 8; j++) {
                float in = In[ci][tn + 32 * j];
                acc[0][j] += w4.x * in;
                acc[1][j] += w4.y * in;
                acc[2][j] += w4.z * in;
                acc[3][j] += w4.w * in;
            }
        }
    }
    int p = pq >> 1, q = pq & 1;
    int GIN = 1 << gsh;
    #pragma unroll
    for (int q2 = 0; q2 < 4; q2++) {
        int o = ot * 32 + tc * 4 + q2;
        float bias = bt[l * CO + o];
        float* orow = xout + (size_t)(lb * CO + o) * (4 * SPIN);
        #pragma unroll
        for (int j = 0; j < 8; j++) {
            int n = ntile * 256 + tn + 32 * j;
            int h = n >> gsh, w = n & (GIN - 1);
            orow[(2 * h + p) * (2 * GIN) + 2 * w + q] = acc[q2][j] + bias;
        }
    }
}

// ---------------- T1 f32 [lb][ci=128][n=1024] -> bf16 t1B [lb][n][ci] ----------------
__global__ __launch_bounds__(256) void kt1cvt(float* __restrict__ ws) {
    __shared__ float Ld[64][65];
    unsigned short* t1B = (unsigned short*)(ws + OFF_T2);
    int bid = blockIdx.x;
    int ntile = bid & 15;
    int r = bid >> 4;
    int ct = r & 1;
    int lb = r >> 1;
    int t = threadIdx.x;
    const float* t1p = ws + OFF_T1 + (size_t)lb * HH * 1024;
    #pragma unroll
    for (int i = 0; i < 4; i++) {
        int f = t + i * 256;
        int row = f >> 4, c4 = f & 15;
        float4 v = *(const float4*)(t1p + (size_t)(ct * 64 + row) * 1024 + ntile * 64 + c4 * 4);
        *(float4*)&Ld[row][c4 * 4] = v;
    }
    __syncthreads();
    #pragma unroll
    for (int i = 0; i < 2; i++) {
        int f = t + i * 256;
        int row = f >> 3, seg = f & 7;
        unsigned int pk[4];
        #pragma unroll
        for (int e = 0; e < 4; e++) {
            unsigned int lo = f2bf(Ld[seg * 8 + 2 * e][row]);
            unsigned int hi = f2bf(Ld[seg * 8 + 2 * e + 1][row]);
            pk[e] = lo | (hi << 16);
        }
        uint4 o = make_uint4(pk[0], pk[1], pk[2], pk[3]);
        *(uint4*)(t1B + ((size_t)(lb * 1024 + ntile * 64 + row)) * HH + ct * 64 + seg * 8) = o;
    }
}

// ---------------- weight repack: lw2 f32 [l][co][ci][9] -> bf16 [l][tap][co][ci] -----
__global__ __launch_bounds__(256) void kw2cvt(const float* __restrict__ lw2, float* __restrict__ ws) {
    unsigned short* w2B = (unsigned short*)(ws + OFF_T2) + T1BSH;
    int bid = blockIdx.x;
    int l = bid / MD, co = bid % MD;
    int t = threadIdx.x;
    if (t < HH) {
        int ci = t;
        const float* src = lw2 + ((size_t)(l * MD + co) * HH + ci) * 9;
        #pragma unroll
        for (int tap = 0; tap < 9; tap++) {
            w2B[((size_t)((l * 9 + tap) * MD + co)) * HH + ci] = f2bf(src[tap]);
        }
    }
}

// ------- conv2 MFMA, split-K x2: 64co x 256n per block, 9 of 18 kc-chunks each -------
__global__ __launch_bounds__(256) void kconv2m(float* __restrict__ ws) {
    __shared__ __align__(16) unsigned short Ab[64][72];
    __shared__ __align__(16) unsigned short Bb[256][72];
    int bid = blockIdx.x;
    int s = bid & 1;
    int ntile = (bid >> 1) & 3;
    int lb = bid >> 3;
    int l = lb >> 4;
    int t = threadIdx.x;
    int lane = t & 63;
    int wave = t >> 6;
    int fr = lane & 15, fq = lane >> 4;
    const unsigned short* t1B = (const unsigned short*)(ws + OFF_T2);
    const unsigned short* w2B = (const unsigned short*)(ws + OFF_T2) + T1BSH;

    f32x4 acc[4][4];
    #pragma unroll
    for (int mi = 0; mi < 4; mi++)
        #pragma unroll
        for (int ni = 0; ni < 4; ni++) acc[mi][ni] = (f32x4){0.f, 0.f, 0.f, 0.f};

    for (int g = s * 9; g < s * 9 + 9; ++g) {
        int tap = g >> 1;
        int kc = (g & 1) * 64;
        int dy = tap / 3 - 1, dx = tap % 3 - 1;
        const unsigned short* wpl = w2B + (size_t)((l * 9 + tap) * MD) * HH;
        __syncthreads();
        #pragma unroll
        for (int i = 0; i < 2; i++) {
            int f = t + i * 256;
            int row = f >> 3, seg = f & 7;
            uint4 v = *(const uint4*)(wpl + (size_t)row * HH + kc + seg * 8);
            *(uint4*)&Ab[row][seg * 8] = v;
        }
        #pragma unroll
        for (int i = 0; i < 8; i++) {
            int f = t + i * 256;
            int row = f >> 3, seg = f & 7;
            int n = ntile * 256 + row;
            int y = (n >> 5) + dy, x = (n & 31) + dx;
            bool ok = ((unsigned)y < 32u) && ((unsigned)x < 32u);
            uint4 v = make_uint4(0u, 0u, 0u, 0u);
            if (ok) v = *(const uint4*)(t1B + ((size_t)(lb * 1024 + y * 32 + x)) * HH + kc + seg * 8);
            *(uint4*)&Bb[row][seg * 8] = v;
        }
        __syncthreads();
        #pragma unroll
        for (int kk = 0; kk < 64; kk += 32) {
            bf16x8 af[4], bfv[4];
            #pragma unroll
            for (int mi = 0; mi < 4; mi++)
                af[mi] = *(const bf16x8*)&Ab[mi * 16 + fr][kk + fq * 8];
            #pragma unroll
            for (int ni = 0; ni < 4; ni++)
                bfv[ni] = *(const bf16x8*)&Bb[wave * 64 + ni * 16 + fr][kk + fq * 8];
            #pragma unroll
            for (int mi = 0; mi < 4; mi++)
                #pragma unroll
                for (int ni = 0; ni < 4; ni++)
                    acc[mi][ni] = __builtin_amdgcn_mfma_f32_16x16x32_bf16(af[mi], bfv[ni], acc[mi][ni], 0, 0, 0);
        }
    }
    float* dst = (s == 1) ? (ws + OFF_X2 + (size_t)lb * MD * 1024)
                          : (ws + OFF_C2P + (size_t)lb * MD * 1024);
    #pragma unroll
    for (int mi = 0; mi < 4; mi++) {
        #pragma unroll
        for (int ni = 0; ni < 4; ni++) {
            int gn = ntile * 256 + wave * 64 + ni * 16 + fr;
            #pragma unroll
            for (int rr = 0; rr < 4; rr++) {
                int co = mi * 16 + fq * 4 + rr;
                dst[(size_t)co * 1024 + gn] = acc[mi][ni][rr];
            }
        }
    }
}

// ---------------- reduce conv2 partial into X2 ----------------
__global__ __launch_bounds__(256) void kc2red(float* __restrict__ ws) {
    size_t i = ((size_t)blockIdx.x * 256 + threadIdx.x) * 8;
    float4 a0 = *(float4*)(ws + OFF_X2 + i);
    float4 a1 = *(float4*)(ws + OFF_X2 + i + 4);
    const float* p = ws + OFF_C2P + i;
    float4 b0 = *(const float4*)p;
    float4 b1 = *(const float4*)(p + 4);
    a0.x += b0.x; a0.y += b0.y; a0.z += b0.z; a0.w += b0.w;
    a1.x += b1.x; a1.y += b1.y; a1.z += b1.z; a1.w += b1.w;
    *(float4*)(ws + OFF_X2 + i) = a0;
    *(float4*)(ws + OFF_X2 + i + 4) = a1;
}

// ---------------- conv3 1x1 64->2 + bias ----------------
__global__ __launch_bounds__(256) void kconv3(const float* __restrict__ lw3,
                                              const float* __restrict__ lb3,
                                              float* __restrict__ ws) {
    __shared__ float w3s[2][64];
    int bid = blockIdx.x;
    int tile = bid & 15;
    int lb = bid >> 4;
    int l = lb >> 4;
    int t = threadIdx.x;
    if (t < 128) w3s[t >> 6][t & 63] = lw3[(size_t)(l * 2 + (t >> 6)) * MD + (t & 63)];
    __syncthreads();
    const float* t2p = ws + OFF_T2 + (size_t)lb * MD * 4096;
    int hw = tile * 256 + t;
    float a0 = lb3[l * 2], a1 = lb3[l * 2 + 1];
    for (int c2 = 0; c2 < MD; c2++) {
        float v = t2p[(size_t)c2 * 4096 + hw];
        a0 += v * w3s[0][c2];
        a1 += v * w3s[1][c2];
    }
    float* r3 = ws + OFF_RAW3 + (size_t)lb * 2 * 4096;
    r3[hw] = a0;
    r3[4096 + hw] = a1;
}

// ---------------- pool 4x4 + channel softmax -> patch outputs ----------------
__global__ __launch_bounds__(256) void kpool(const float* __restrict__ ws, float* __restrict__ out) {
    int lb = blockIdx.x;
    int t = threadIdx.x;
    int gy = t >> 4, gx = t & 15;
    const float* r3 = ws + OFF_RAW3 + (size_t)lb * 2 * 4096;
    float pl[2];
    #pragma unroll
    for (int ch = 0; ch < 2; ch++) {
        const float* basep = r3 + ch * 4096;
        float s = 0.f;
        #pragma unroll
        for (int dy = 0; dy < 4; dy++)
            #pragma unroll
            for (int dx = 0; dx < 4; dx++)
                s += basep[(gy * 4 + dy) * 64 + gx * 4 + dx];
        pl[ch] = s * (1.f / 16.f);
    }
    out[O_PLG + lb * NNQ + t] = pl[1] - pl[0];
    out[O_PSC + lb * NNQ + t] = 1.f / (1.f + expf(pl[0] - pl[1]));
}

// ---------------- bilinear resize 64x64 -> 240x240 (half-pixel, clamped) -------------
__global__ __launch_bounds__(256) void kresize(const float* __restrict__ ws, float* __restrict__ out) {
    int id = blockIdx.x * 256 + threadIdx.x;
    int ox = id % IMGSZ;
    int tmp = id / IMGSZ;
    int oy = tmp % IMGSZ;
    int tmp2 = tmp / IMGSZ;
    int ch = tmp2 & 1;
    int lb = tmp2 >> 1;
    const float S = 64.f / 240.f;
    float xs = fminf(fmaxf((ox + 0.5f) * S - 0.5f, 0.f), 63.f);
    float ys = fminf(fmaxf((oy + 0.5f) * S - 0.5f, 0.f), 63.f);
    int x0 = (int)xs, y0 = (int)ys;
    float fx = xs - x0, fy = ys - y0;
    int x1 = min(x0 + 1, 63), y1 = min(y0 + 1, 63);
    const float* basep = ws + OFF_RAW3 + (size_t)(lb * 2 + ch) * 4096;
    float v00 = basep[y0 * 64 + x0], v01 = basep[y0 * 64 + x1];
    float v10 = basep[y1 * 64 + x0], v11 = basep[y1 * 64 + x1];
    float v = (1.f - fy) * ((1.f - fx) * v00 + fx * v01) + fy * ((1.f - fx) * v10 + fx * v11);
    out[O_LOC + id] = v;
}

// ---------------- GAP/GMP pooled vector (many-block, coalesced) ----------------
__global__ __launch_bounds__(256) void kgap(float* __restrict__ ws,
                                            const float* __restrict__ pool_logits) {
    int bid = blockIdx.x;
    int dchunk = bid % 12;
    int lb = bid / 12;
    int l = lb >> 4;
    int t = threadIdx.x;
    int r = t >> 2, p = t & 3;
    int d = dchunk * 64 + r;
    const float* row = ws + OFF_CMAP + (size_t)lb * DD * NNQ + (size_t)d * NNQ + p * 64;
    float s = 0.f, mx = -1e30f, mn = 1e30f;
    #pragma unroll
    for (int i = 0; i < 16; i++) {
        float4 v = *(const float4*)(row + i * 4);
        s += v.x + v.y + v.z + v.w;
        mx = fmaxf(mx, fmaxf(fmaxf(v.x, v.y), fmaxf(v.z, v.w)));
        mn = fminf(mn, fminf(fminf(v.x, v.y), fminf(v.z, v.w)));
    }
    s += __shfl_xor(s, 1, 64); s += __shfl_xor(s, 2, 64);
    mx = fmaxf(mx, __shfl_xor(mx, 1, 64)); mx = fmaxf(mx, __shfl_xor(mx, 2, 64));
    mn = fminf(mn, __shfl_xor(mn, 1, 64)); mn = fminf(mn, __shfl_xor(mn, 2, 64));
    if (p == 0) {
        float p0 = pool_logits[l * 2], p1 = pool_logits[l * 2 + 1];
        float mxp = fmaxf(p0, p1);
        float e0 = expf(p0 - mxp), e1 = expf(p1 - mxp);
        float pw0 = e0 / (e0 + e1), pw1 = e1 / (e0 + e1);
        const float* bns = ws + OFF_BNSH + l * DD;
        const float* bnb = ws + OFF_BNSH + LLY * DD + l * DD;
        float scv = bns[d], bov = bnb[d];
        float gap = scv * (s * (1.f / NNQ)) + bov;
        float gmp = (scv >= 0.f) ? (scv * mx + bov) : (scv * mn + bov);
        ws[OFF_PGL + lb * DD + d] = pw0 * gap + pw1 * gmp;
    }
}

// ---------------- global head tail: MLP + LN from pooled ----------------
__global__ __launch_bounds__(256) void kglob2(const float* __restrict__ ws,
                                              const float* __restrict__ pool_logits,
                                              const float* __restrict__ mw1,
                                              const float* __restrict__ mlng,
                                              const float* __restrict__ mlnb,
                                              const float* __restrict__ mw2,
                                              const float* __restrict__ mb2,
                                              float* __restrict__ out) {
    __shared__ float pooled[DD];
    __shared__ float zbuf[HH];
    __shared__ float hbuf[HH];
    __shared__ float sm[4];
    int lb = blockIdx.x;
    int l = lb >> 4;
    int b = lb & 15;
    int t = threadIdx.x;
    float p0 = pool_logits[l * 2], p1 = pool_logits[l * 2 + 1];
    float mx = fmaxf(p0, p1);
    float e0 = expf(p0 - mx), e1 = expf(p1 - mx);
    float pw0 = e0 / (e0 + e1), pw1 = e1 / (e0 + e1);
    if (b == 0 && t < 2) out[O_PW + l * 2 + t] = (t == 0) ? pw0 : pw1;

    for (int d = t; d < DD; d += 256) pooled[d] = ws[OFF_PGL + lb * DD + d];
    __syncthreads();
    if (t < HH) {
        const float* wrow = mw1 + (size_t)(l * HH + t) * DD;
        float a = 0.f;
        for (int d2 = 0; d2 < DD; d2++) a += pooled[d2] * wrow[d2];
        zbuf[t] = a;
    }
    __syncthreads();
    float zv = (t < HH) ? zbuf[t] : 0.f;
    float s1r = blockReduceSum(zv, sm);
    float s2r = blockReduceSum(zv * zv, sm);
    float mean = s1r * (1.f / HH);
    float var = s2r * (1.f / HH) - mean * mean;
    float rstd = rsqrtf(var + 1e-5f);
    if (t < HH) {
        float h = (zbuf[t] - mean) * rstd * mlng[l * HH + t] + mlnb[l * HH + t];
        hbuf[t] = fmaxf(h, 0.f);
    }
    __syncthreads();
    float hv = (t < HH) ? hbuf[t] : 0.f;
    float w0v = (t < HH) ? mw2[(size_t)(l * 2 + 0) * HH + t] : 0.f;
    float w1v = (t < HH) ? mw2[(size_t)(l * 2 + 1) * HH + t] : 0.f;
    float s0 = blockReduceSum(hv * w0v, sm);
    float s1 = blockReduceSum(hv * w1v, sm);
    if (t == 0) out[O_GLG + lb] = (s1 + mb2[l * 2 + 1]) - (s0 + mb2[l * 2]);
}

extern "C" void kernel_launch(void* const* d_in, const int* in_sizes, int n_in,
                              void* d_out, int out_size, void* d_ws, size_t ws_size,
                              hipStream_t stream) {
    const float* query      = (const float*)d_in[0];
    const float* prompt     = (const float*)d_in[1];
    const float* sharebn_g  = (const float*)d_in[2];
    const float* sharebn_b  = (const float*)d_in[3];
    const float* lw1        = (const float*)d_in[4];
    const float* lbn1g      = (const float*)d_in[5];
    const float* lbn1b      = (const float*)d_in[6];
    const float* lwt1       = (const float*)d_in[7];
    const float* lbt1       = (const float*)d_in[8];
    const float* lw2        = (const float*)d_in[9];
    const float* lbn2g      = (const float*)d_in[10];
    const float* lbn2b      = (const float*)d_in[11];
    const float* lwt2       = (const float*)d_in[12];
    const float* lbt2       = (const float*)d_in[13];
    const float* lw3        = (const float*)d_in[14];
    const float* lb3        = (const float*)d_in[15];
    const float* pool_logits= (const float*)d_in[16];
    const float* mw1        = (const float*)d_in[17];
    const float* mlng       = (const float*)d_in[18];
    const float* mlnb       = (const float*)d_in[19];
    const float* mw2        = (const float*)d_in[20];
    const float* mb2        = (const float*)d_in[21];
    float* out = (float*)d_out;
    float* ws = (float*)d_ws;

    hipLaunchKernelGGL(knormq, dim3(LLY*BB*NNQ), dim3(192), 0, stream, query, ws);
    hipLaunchKernelGGL(ksimm, dim3(LBTOT*16), dim3(512), 0, stream, prompt, ws);
    hipLaunchKernelGGL(kpost, dim3(LBTOT*16), dim3(256), 0, stream, query, prompt, ws, out);
    hipLaunchKernelGGL(kbnstats, dim3(LLY*DD), dim3(256), 0, stream,
                       ws + OFF_CMAP, DD, NNQ, sharebn_g, sharebn_b, ws + OFF_BNSH);
    // conv1 via MFMA, split-K x6
    hipLaunchKernelGGL(kw1cvt, dim3(LLY*HH), dim3(256), 0, stream, lw1, ws);
    hipLaunchKernelGGL(kbn1cvt, dim3(LBTOT*48), dim3(256), 0, stream, ws);
    hipLaunchKernelGGL(kconv1m, dim3(LBTOT*12), dim3(256), 0, stream, ws);
    hipLaunchKernelGGL(kc1red, dim3(768), dim3(256), 0, stream, ws);
    hipLaunchKernelGGL(kbnstats, dim3(LLY*HH), dim3(256), 0, stream,
                       ws + OFF_X1, HH, 256, lbn1g, lbn1b, ws + OFF_BN1);
    hipLaunchKernelGGL(kconvT, dim3(LBTOT*16), dim3(256), 0, stream,
                       lwt1, lbt1, ws + OFF_X1, ws + OFF_BN1, ws + OFF_T1, HH, HH, 4, 1, 4);
    // conv2 via MFMA, split-K x2
    hipLaunchKernelGGL(kt1cvt, dim3(LBTOT*32), dim3(256), 0, stream, ws);
    hipLaunchKernelGGL(kw2cvt, dim3(LLY*MD), dim3(256), 0, stream, lw2, ws);
    hipLaunchKernelGGL(kconv2m, dim3(LBTOT*8), dim3(256), 0, stream, ws);
    hipLaunchKernelGGL(kc2red, dim3(1536), dim3(256), 0, stream, ws);
    hipLaunchKernelGGL(kbnstats, dim3(LLY*MD), dim3(256), 0, stream,
                       ws + OFF_X2, MD, 1024, lbn2g, lbn2b, ws + OFF_BN2);
    hipLaunchKernelGGL(kconvT, dim3(LBTOT*32), dim3(256), 0, stream,
                       lwt2, lbt2, ws + OFF_X2, ws + OFF_BN2, ws + OFF_T2, MD, MD, 5, 4, 2);
    hipLaunchKernelGGL(kconv3, dim3(LBTOT*16), dim3(256), 0, stream, lw3, lb3, ws);
    hipLaunchKernelGGL(kpool, dim3(LBTOT), dim3(256), 0, stream, ws, out);
    hipLaunchKernelGGL(kresize, dim3(LLY*BB*2*IMGSZ*IMGSZ/256), dim3(256), 0, stream, ws, out);
    hipLaunchKernelGGL(kgap, dim3(LBTOT*12), dim3(256), 0, stream, ws, pool_logits);
    hipLaunchKernelGGL(kglob2, dim3(LBTOT), dim3(256), 0, stream,
                       ws, pool_logits, mw1, mlng, mlnb, mw2, mb2, out);
}

// Round 10
// 530.812 us; speedup vs baseline: 1.0715x; 1.0715x over previous
//
#include <hip/hip_runtime.h>
#include <hip/hip_bf16.h>
#include <math.h>

#define LLY 3
#define BB 16
#define NNQ 256
#define DD 768
#define MMP 2048
#define HH 128
#define MD 64
#define IMGSZ 240
#define LBTOT (LLY*BB)

// ---------------- workspace layout (floats) ----------------
#define OFF_INVQ 0
#define OFF_INVP (OFF_INVQ + LLY*BB*NNQ)
#define OFF_CMAP (OFF_INVP + LLY*BB*MMP)
#define OFF_BNSH (OFF_CMAP + LLY*BB*DD*NNQ)
#define OFF_X1   (OFF_BNSH + 2*LLY*DD)
#define OFF_BN1  (OFF_X1 + LLY*BB*HH*256)
#define OFF_T1   (OFF_BN1 + 2*LLY*HH)
#define OFF_X2   (OFF_T1 + LLY*BB*HH*1024)
#define OFF_BN2  (OFF_X2 + LLY*BB*MD*1024)
#define OFF_T2   (OFF_BN2 + 2*LLY*MD)
#define OFF_RAW3 (OFF_T2 + LLY*BB*MD*4096)
#define WS_FLOATS (OFF_RAW3 + LLY*BB*2*4096)
#define T1BSH (LBTOT*1024*HH)      // shorts
#define SQH   (LBTOT*NNQ*DD)       // shorts per q-split plane
#define OFF_C1P (OFF_T2 + 4718592)
#define OFF_C2P (OFF_T2 + 3256320)
#define OFF_PGL OFF_X1

// ---------------- output layout (floats) ----------------
#define O_RES 0
#define O_PSC (O_RES + LLY*BB*NNQ)
#define O_PLG (O_PSC + LLY*BB*NNQ)
#define O_GLG (O_PLG + LLY*BB*NNQ)
#define O_LOC (O_GLG + LLY*BB)
#define O_PW  (O_LOC + LLY*BB*2*IMGSZ*IMGSZ)
#define O_IDX (O_PW + LLY*2)
#define O_ALN (O_IDX + LLY*BB*NNQ)

typedef __attribute__((ext_vector_type(8))) short bf16x8;
typedef __attribute__((ext_vector_type(4))) float f32x4;

__device__ __forceinline__ unsigned short f2bf(float f) {
    __hip_bfloat16 h = __float2bfloat16(f);
    unsigned short u;
    __builtin_memcpy(&u, &h, sizeof(u));
    return u;
}
__device__ __forceinline__ float bf2f(unsigned short h) {
    return __uint_as_float(((unsigned int)h) << 16);
}

__device__ __forceinline__ float blockReduceSum(float v, float* sm) {
    for (int o = 32; o; o >>= 1) v += __shfl_down(v, o, 64);
    __syncthreads();
    if ((threadIdx.x & 63) == 0) sm[threadIdx.x >> 6] = v;
    __syncthreads();
    return sm[0] + sm[1] + sm[2] + sm[3];
}

// ------- fused: query row L2-norm + normalized bf16 hi/lo split (into T2 region) -----
__global__ __launch_bounds__(192) void knormq(const float* __restrict__ query,
                                              float* __restrict__ ws) {
    __shared__ float sm[3];
    int row = blockIdx.x;
    int t = threadIdx.x;
    float4 v = *(const float4*)(query + (size_t)row * DD + t * 4);
    float ss = v.x * v.x + v.y * v.y + v.z * v.z + v.w * v.w;
    for (int o = 32; o; o >>= 1) ss += __shfl_down(ss, o, 64);
    if ((t & 63) == 0) sm[t >> 6] = ss;
    __syncthreads();
    ss = sm[0] + sm[1] + sm[2];
    float iv = 1.0f / fmaxf(sqrtf(ss), 1e-12f);
    if (t == 0) ws[OFF_INVQ + row] = iv;
    unsigned short* qh = (unsigned short*)(ws + OFF_T2);
    unsigned short* ql = qh + SQH;
    float e[4] = {v.x * iv, v.y * iv, v.z * iv, v.w * iv};
    unsigned int hp[2], lp[2];
    #pragma unroll
    for (int j = 0; j < 2; j++) {
        unsigned short h0 = f2bf(e[2*j]), h1 = f2bf(e[2*j+1]);
        unsigned short l0 = f2bf(e[2*j] - bf2f(h0)), l1 = f2bf(e[2*j+1] - bf2f(h1));
        hp[j] = (unsigned int)h0 | ((unsigned int)h1 << 16);
        lp[j] = (unsigned int)l0 | ((unsigned int)l1 << 16);
    }
    *(uint2*)(qh + (size_t)row * DD + t * 4) = make_uint2(hp[0], hp[1]);
    *(uint2*)(ql + (size_t)row * DD + t * 4) = make_uint2(lp[0], lp[1]);
}

// ---- sim GEMM: 128p x 256q block, 8 waves of 64x64, fused p-norm, 40-short stride ---
__global__ __launch_bounds__(512) void ksimm(const float* __restrict__ prompt, float* __restrict__ ws) {
    __shared__ __align__(16) unsigned short Ah[128][40];
    __shared__ __align__(16) unsigned short Al[128][40];
    __shared__ __align__(16) unsigned short Bh[256][40];
    __shared__ __align__(16) unsigned short Bl[256][40];
    __shared__ float invL[128];
    int bid = blockIdx.x;
    int mt = bid & 15;
    int lb = bid >> 4;
    int t = threadIdx.x;
    int lane = t & 63, wave = t >> 6;
    int wm = wave >> 2, wn = wave & 3;
    int fr = lane & 15, fq = lane >> 4;
    const unsigned short* qh = (const unsigned short*)(ws + OFF_T2);
    const unsigned short* ql = qh + SQH;
    const float* pbase = prompt + (size_t)lb * MMP * DD + (size_t)(mt * 128) * DD;

    float ssq[2] = {0.f, 0.f};

    f32x4 acc[4][4];
    #pragma unroll
    for (int mi = 0; mi < 4; mi++)
        #pragma unroll
        for (int ni = 0; ni < 4; ni++) acc[mi][ni] = (f32x4){0.f, 0.f, 0.f, 0.f};

    for (int kc = 0; kc < DD; kc += 32) {
        __syncthreads();
        #pragma unroll
        for (int i = 0; i < 2; i++) {          // stage P: 128 x 32 f32 -> hi/lo (+ssq)
            int f = t + i * 512;
            int row = f >> 3, c4 = f & 7;
            float4 v = *(const float4*)(pbase + (size_t)row * DD + kc + c4 * 4);
            ssq[i] += v.x * v.x + v.y * v.y + v.z * v.z + v.w * v.w;
            unsigned short h0 = f2bf(v.x), h1 = f2bf(v.y), h2 = f2bf(v.z), h3 = f2bf(v.w);
            unsigned short l0 = f2bf(v.x - bf2f(h0)), l1 = f2bf(v.y - bf2f(h1));
            unsigned short l2 = f2bf(v.z - bf2f(h2)), l3 = f2bf(v.w - bf2f(h3));
            uint2 hp = make_uint2((unsigned int)h0 | ((unsigned int)h1 << 16),
                                  (unsigned int)h2 | ((unsigned int)h3 << 16));
            uint2 lp = make_uint2((unsigned int)l0 | ((unsigned int)l1 << 16),
                                  (unsigned int)l2 | ((unsigned int)l3 << 16));
            *(uint2*)&Ah[row][c4 * 4] = hp;
            *(uint2*)&Al[row][c4 * 4] = lp;
        }
        #pragma unroll
        for (int i = 0; i < 2; i++) {          // stage Q: 256 x 32 bf16 hi/lo
            int f = t + i * 512;
            int row = f >> 2, sg = f & 3;
            size_t go = (size_t)(lb * NNQ + row) * DD + kc + sg * 8;
            *(uint4*)&Bh[row][sg * 8] = *(const uint4*)(qh + go);
            *(uint4*)&Bl[row][sg * 8] = *(const uint4*)(ql + go);
        }
        __syncthreads();
        bf16x8 ah[4], al4[4], bh[4], bl4[4];
        #pragma unroll
        for (int mi = 0; mi < 4; mi++) {
            ah[mi]  = *(const bf16x8*)&Ah[wm * 64 + mi * 16 + fr][fq * 8];
            al4[mi] = *(const bf16x8*)&Al[wm * 64 + mi * 16 + fr][fq * 8];
        }
        #pragma unroll
        for (int ni = 0; ni < 4; ni++) {
            bh[ni]  = *(const bf16x8*)&Bh[wn * 64 + ni * 16 + fr][fq * 8];
            bl4[ni] = *(const bf16x8*)&Bl[wn * 64 + ni * 16 + fr][fq * 8];
        }
        #pragma unroll
        for (int mi = 0; mi < 4; mi++)
            #pragma unroll
            for (int ni = 0; ni < 4; ni++) {
                acc[mi][ni] = __builtin_amdgcn_mfma_f32_16x16x32_bf16(ah[mi],  bh[ni],  acc[mi][ni], 0, 0, 0);
                acc[mi][ni] = __builtin_amdgcn_mfma_f32_16x16x32_bf16(ah[mi],  bl4[ni], acc[mi][ni], 0, 0, 0);
                acc[mi][ni] = __builtin_amdgcn_mfma_f32_16x16x32_bf16(al4[mi], bh[ni],  acc[mi][ni], 0, 0, 0);
            }
    }
    // prompt norms: reduce ssq across the 8 staging lanes per row
    #pragma unroll
    for (int i = 0; i < 2; i++) {
        float s = ssq[i];
        s += __shfl_xor(s, 1, 64);
        s += __shfl_xor(s, 2, 64);
        s += __shfl_xor(s, 4, 64);
        if ((t & 7) == 0) {
            int row = (t >> 3) + 64 * i;
            float iv = 1.0f / fmaxf(sqrtf(s), 1e-12f);
            invL[row] = iv;
            ws[OFF_INVP + lb * MMP + mt * 128 + row] = iv;
        }
    }
    __syncthreads();
    // fold invp + per-wave argmax over 64 prompts (ascending m within wave)
    float* bestv = ws + OFF_X1;
    float* besti = ws + OFF_X1 + (size_t)LBTOT * NNQ * 32;
    #pragma unroll
    for (int ni = 0; ni < 4; ni++) {
        float bv = -1e30f; int bi = 0;
        #pragma unroll
        for (int mi = 0; mi < 4; mi++)
            #pragma unroll
            for (int rr = 0; rr < 4; rr++) {
                int lm = wm * 64 + mi * 16 + fq * 4 + rr;
                float s = acc[mi][ni][rr] * invL[lm];
                int m = mt * 128 + lm;
                if (s > bv) { bv = s; bi = m; }
            }
        #pragma unroll
        for (int o = 16; o <= 32; o <<= 1) {
            float ov = __shfl_xor(bv, o, 64);
            int oi = __shfl_xor(bi, o, 64);
            if (ov > bv || (ov == bv && oi < bi)) { bv = ov; bi = oi; }
        }
        if (fq == 0) {
            int q = wn * 64 + ni * 16 + fr;
            size_t slot = (size_t)(lb * NNQ + q) * 32 + wm * 16 + mt;
            bestv[slot] = bv;
            besti[slot] = (float)bi;
        }
    }
}

// --- argmax finalize + residual/idx/aligned/ctx; cmap written via LDS transpose ------
__global__ __launch_bounds__(256) void kpost(const float* __restrict__ query,
                                             const float* __restrict__ prompt,
                                             float* __restrict__ ws,
                                             float* __restrict__ out) {
    __shared__ float red_v[16];
    __shared__ int   red_i[16];
    __shared__ float Lctx[DD * 17];     // [d][nn] padded to 17 for bank spread
    int bid = blockIdx.x;
    int nt = bid & 15;
    int lb = bid >> 4;
    int t = threadIdx.x;
    const float* bestv = ws + OFF_X1;
    const float* besti = ws + OFF_X1 + (size_t)LBTOT * NNQ * 32;
    if (t < 16) {
        int q = nt * 16 + t;
        const float* bv = bestv + (size_t)(lb * NNQ + q) * 32;
        const float* bi = besti + (size_t)(lb * NNQ + q) * 32;
        float best = -1e30f; int bidx2 = 0;
        for (int mtt = 0; mtt < 16; mtt++)
            #pragma unroll
            for (int wm = 0; wm < 2; wm++) {   // (mt,wm) lexicographic = ascending m
                float v = bv[wm * 16 + mtt];
                if (v > best) { best = v; bidx2 = (int)bi[wm * 16 + mtt]; }
            }
        red_v[t] = best; red_i[t] = bidx2;
        out[O_RES + lb * NNQ + q] = 0.5f * (1.0f - best);
        out[O_IDX + lb * NNQ + q] = (float)bidx2;
    }
    __syncthreads();
    const float* qbase = query + (size_t)(lb * NNQ + nt * 16) * DD;
    const float* pbase = prompt + (size_t)lb * MMP * DD;
    const float* invq = ws + OFF_INVQ + lb * NNQ + nt * 16;
    const float* invp = ws + OFF_INVP + lb * MMP;
    int c = t & 15;
    int nn = t >> 4;
    int gn = nt * 16 + nn;
    int midx = red_i[nn];
    float ip = invp[midx];
    float iq = invq[nn];
    const float* prow = pbase + (size_t)midx * DD;
    const float* qrow = qbase + (size_t)nn * DD;
    float* aln = out + O_ALN + (size_t)(lb * NNQ + gn) * DD;
    for (int jj = 0; jj < DD / 16; jj++) {
        int d = c + jj * 16;
        float pvr = prow[d];
        float qv = qrow[d] * iq;
        float av = pvr * ip;
        float cx = qv + fabsf(qv - av);
        aln[d] = pvr;
        Lctx[d * 17 + nn] = cx;
    }
    __syncthreads();
    // transposed write: 16 consecutive n per d -> 64B segments
    float* cm = ws + OFF_CMAP + (size_t)lb * DD * NNQ + nt * 16;
    int nl = t & 15, dd = t >> 4;
    for (int jj = 0; jj < DD / 16; jj++) {
        int d = jj * 16 + dd;
        cm[(size_t)d * NNQ + nl] = Lctx[d * 17 + nl];
    }
}

// ---------------- BN batch stats (per l,c over B x SP), biased var ----------------
__global__ __launch_bounds__(256) void kbnstats(const float* __restrict__ x, int C, int SP,
                                                const float* __restrict__ g,
                                                const float* __restrict__ b,
                                                float* __restrict__ outSB) {
    __shared__ float sm[4];
    int bid = blockIdx.x;
    int c = bid % C;
    int l = bid / C;
    int t = threadIdx.x;
    float s = 0.f, sq = 0.f;
    for (int bb2 = 0; bb2 < BB; ++bb2) {
        const float* p = x + ((size_t)(l * BB + bb2) * C + c) * SP;
        for (int i = t; i < SP; i += 256) { float v = p[i]; s += v; sq += v * v; }
    }
    s = blockReduceSum(s, sm);
    sq = blockReduceSum(sq, sm);
    if (t == 0) {
        float inv = 1.0f / (float)(BB * SP);
        float m = s * inv;
        float var = sq * inv - m * m;
        float sc = g[l * C + c] * rsqrtf(var + 1e-5f);
        float bo = b[l * C + c] - m * sc;
        outSB[l * C + c] = sc;
        outSB[LLY * C + l * C + c] = bo;
    }
}

// ---------------- weight repack: lw1 f32 [l][co][ci][9] -> bf16 [l][tap][co][ci] -----
__global__ __launch_bounds__(256) void kw1cvt(const float* __restrict__ lw1, float* __restrict__ ws) {
    unsigned short* w1B = (unsigned short*)(ws + OFF_X2);
    int bid = blockIdx.x;
    int l = bid / HH, co = bid % HH;
    int t = threadIdx.x;
    for (int c0 = 0; c0 < DD; c0 += 256) {
        int ci = c0 + t;
        const float* src = lw1 + ((size_t)(l * HH + co) * DD + ci) * 9;
        #pragma unroll
        for (int tap = 0; tap < 9; tap++) {
            w1B[((size_t)((l * 9 + tap) * HH + co)) * DD + ci] = f2bf(src[tap]);
        }
    }
}

// ---------------- BN-fold + transpose: cmap f32 [lb][ci][n] -> bf16 cmT [lb][n][ci] --
__global__ __launch_bounds__(256) void kbn1cvt(float* __restrict__ ws) {
    __shared__ float Ld[64][65];
    unsigned short* cmT = (unsigned short*)(ws + OFF_T2);
    int bid = blockIdx.x;
    int nt = bid & 3;
    int r = bid >> 2;
    int ct = r % 12;
    int lb = r / 12;
    int l = lb >> 4;
    int t = threadIdx.x;
    const float* cmap = ws + OFF_CMAP + (size_t)lb * DD * NNQ;
    const float* bns = ws + OFF_BNSH + l * DD;
    const float* bnb = ws + OFF_BNSH + LLY * DD + l * DD;
    #pragma unroll
    for (int i = 0; i < 4; i++) {
        int f = t + i * 256;
        int row = f >> 4, c4 = f & 15;
        int ci = ct * 64 + row;
        float4 v = *(const float4*)(cmap + (size_t)ci * NNQ + nt * 64 + c4 * 4);
        float s = bns[ci], bo = bnb[ci];
        Ld[row][c4*4+0] = v.x * s + bo; Ld[row][c4*4+1] = v.y * s + bo;
        Ld[row][c4*4+2] = v.z * s + bo; Ld[row][c4*4+3] = v.w * s + bo;
    }
    __syncthreads();
    #pragma unroll
    for (int i = 0; i < 2; i++) {
        int f = t + i * 256;
        int row = f >> 3, seg = f & 7;
        unsigned int pk[4];
        #pragma unroll
        for (int e = 0; e < 4; e++) {
            unsigned int lo = f2bf(Ld[seg * 8 + 2 * e][row]);
            unsigned int hi = f2bf(Ld[seg * 8 + 2 * e + 1][row]);
            pk[e] = lo | (hi << 16);
        }
        uint4 o = make_uint4(pk[0], pk[1], pk[2], pk[3]);
        *(uint4*)(cmT + ((size_t)(lb * NNQ + nt * 64 + row)) * DD + ct * 64 + seg * 8) = o;
    }
}

// ------- conv1 MFMA, split-K x6: 128co x 128n per block, 18 of 108 kc-chunks each ----
__global__ __launch_bounds__(256) void kconv1m(float* __restrict__ ws) {
    __shared__ __align__(16) unsigned short Ab[128][72];
    __shared__ __align__(16) unsigned short Bb[128][72];
    int bid = blockIdx.x;
    int s = bid % 6;
    int ntile = (bid / 6) & 1;
    int lb = bid / 12;
    int l = lb >> 4;
    int t = threadIdx.x;
    int lane = t & 63;
    int wave = t >> 6;
    int wr = wave >> 1, wc = wave & 1;
    int fr = lane & 15, fq = lane >> 4;
    const unsigned short* w1B = (const unsigned short*)(ws + OFF_X2);
    const unsigned short* cmT = (const unsigned short*)(ws + OFF_T2);

    f32x4 acc[4][4];
    #pragma unroll
    for (int mi = 0; mi < 4; mi++)
        #pragma unroll
        for (int ni = 0; ni < 4; ni++) acc[mi][ni] = (f32x4){0.f, 0.f, 0.f, 0.f};

    for (int g = s * 18; g < s * 18 + 18; ++g) {
        int tap = g / 12;
        int kc = (g % 12) * 64;
        int dy = tap / 3 - 1, dx = tap % 3 - 1;
        const unsigned short* wpl = w1B + (size_t)((l * 9 + tap) * HH) * DD;
        __syncthreads();
        #pragma unroll
        for (int i = 0; i < 4; i++) {
            int f = t + i * 256;
            int row = f >> 3, seg = f & 7;
            uint4 v = *(const uint4*)(wpl + (size_t)row * DD + kc + seg * 8);
            *(uint4*)&Ab[row][seg * 8] = v;
        }
        #pragma unroll
        for (int i = 0; i < 4; i++) {
            int f = t + i * 256;
            int row = f >> 3, seg = f & 7;
            int n = ntile * 128 + row;
            int y = (n >> 4) + dy, x = (n & 15) + dx;
            bool ok = ((unsigned)y < 16u) && ((unsigned)x < 16u);
            uint4 v = make_uint4(0u, 0u, 0u, 0u);
            if (ok) v = *(const uint4*)(cmT + ((size_t)(lb * NNQ + y * 16 + x)) * DD + kc + seg * 8);
            *(uint4*)&Bb[row][seg * 8] = v;
        }
        __syncthreads();
        #pragma unroll
        for (int kk = 0; kk < 64; kk += 32) {
            bf16x8 af[4], bfv[4];
            #pragma unroll
            for (int mi = 0; mi < 4; mi++)
                af[mi] = *(const bf16x8*)&Ab[wr * 64 + mi * 16 + fr][kk + fq * 8];
            #pragma unroll
            for (int ni = 0; ni < 4; ni++)
                bfv[ni] = *(const bf16x8*)&Bb[wc * 64 + ni * 16 + fr][kk + fq * 8];
            #pragma unroll
            for (int mi = 0; mi < 4; mi++)
                #pragma unroll
                for (int ni = 0; ni < 4; ni++)
                    acc[mi][ni] = __builtin_amdgcn_mfma_f32_16x16x32_bf16(af[mi], bfv[ni], acc[mi][ni], 0, 0, 0);
        }
    }
    float* dst = (s == 5) ? (ws + OFF_X1 + (size_t)lb * HH * 256)
                          : (ws + OFF_C1P + (size_t)(s * LBTOT + lb) * (HH * 256));
    #pragma unroll
    for (int mi = 0; mi < 4; mi++) {
        #pragma unroll
        for (int ni = 0; ni < 4; ni++) {
            int gn = ntile * 128 + wc * 64 + ni * 16 + fr;
            #pragma unroll
            for (int rr = 0; rr < 4; rr++) {
                int co = wr * 64 + mi * 16 + fq * 4 + rr;
                dst[(size_t)co * 256 + gn] = acc[mi][ni][rr];
            }
        }
    }
}

// ---------------- reduce conv1 partials into X1 ----------------
__global__ __launch_bounds__(256) void kc1red(float* __restrict__ ws) {
    size_t i = ((size_t)blockIdx.x * 256 + threadIdx.x) * 8;
    float4 a0 = *(float4*)(ws + OFF_X1 + i);
    float4 a1 = *(float4*)(ws + OFF_X1 + i + 4);
    #pragma unroll
    for (int s = 0; s < 5; s++) {
        const float* p = ws + OFF_C1P + (size_t)s * (LBTOT * HH * 256) + i;
        float4 b0 = *(const float4*)p;
        float4 b1 = *(const float4*)(p + 4);
        a0.x += b0.x; a0.y += b0.y; a0.z += b0.z; a0.w += b0.w;
        a1.x += b1.x; a1.y += b1.y; a1.z += b1.z; a1.w += b1.w;
    }
    *(float4*)(ws + OFF_X1 + i) = a0;
    *(float4*)(ws + OFF_X1 + i + 4) = a1;
}

// ---------------- convT 2x2 s2 (generic), input = relu(bn(xin)) ----------------
__global__ __launch_bounds__(256) void kconvT(const float* __restrict__ wt,
                                              const float* __restrict__ bt,
                                              const float* __restrict__ xin,
                                              const float* __restrict__ sbsb,
                                              float* __restrict__ xout,
                                              int CI, int CO, int gsh, int nTiles, int oTiles) {
    __shared__ __align__(16) float In[16][256];
    __shared__ __align__(16) float Wc[16][32];
    int bid = blockIdx.x;
    int ntile = bid % nTiles;
    int rem = bid / nTiles;
    int pq = rem & 3; rem >>= 2;
    int ot = rem % oTiles;
    int lb = rem / oTiles;
    int l = lb >> 4;
    int SPIN = 1 << (2 * gsh);
    int t = threadIdx.x, tc = t >> 5, tn = t & 31;
    const float* sc = sbsb + l * CI;
    const float* bo = sbsb + LLY * CI + l * CI;
    float acc[4][8] = {};

    for (int cc = 0; cc < CI; cc += 16) {
        __syncthreads();
        #pragma unroll
        for (int i = 0; i < 4; i++) {
            int fid = t + i * 256;
            int r = fid >> 6, c4 = fid & 63;
            int ci = cc + r;
            float4 v = *(const float4*)(xin + (size_t)(lb * CI + ci) * SPIN + ntile * 256 + c4 * 4);
            float s = sc[ci], bb_ = bo[ci];
            v.x = fmaxf(v.x * s + bb_, 0.f); v.y = fmaxf(v.y * s + bb_, 0.f);
            v.z = fmaxf(v.z * s + bb_, 0.f); v.w = fmaxf(v.w * s + bb_, 0.f);
            *(float4*)&In[r][c4 * 4] = v;
        }
        #pragma unroll
        for (int i = 0; i < 2; i++) {
            int idx = t + i * 256;
            int c_l = idx >> 5, o_l = idx & 31;
            Wc[c_l][o_l] = wt[((size_t)(l * CI + cc + c_l) * CO + ot * 32 + o_l) * 4 + pq];
        }
        __syncthreads();
        #pragma unroll
        for (int ci = 0; ci < 16; ci++) {
            float4 w4 = *(const float4*)&Wc[ci][tc * 4];
            #pragma unroll
            for (int j = 0; j < 8; j++) {
                float in = In[ci][tn + 32 * j];
                acc[0][j] += w4.x * in;
                acc[1][j] += w4.y * in;
                acc[2][j] += w4.z * in;
                acc[3][j] += w4.w * in;
            }
        }
    }
    int p = pq >> 1, q = pq & 1;
    int GIN = 1 << gsh;
    #pragma unroll
    for (int q2 = 0; q2 < 4; q2++) {
        int o = ot * 32 + tc * 4 + q2;
        float bias = bt[l * CO + o];
        float* orow = xout + (size_t)(lb * CO + o) * (4 * SPIN);
        #pragma unroll
        for (int j = 0; j < 8; j++) {
            int n = ntile * 256 + tn + 32 * j;
            int h = n >> gsh, w = n & (GIN - 1);
            orow[(2 * h + p) * (2 * GIN) + 2 * w + q] = acc[q2][j] + bias;
        }
    }
}

// ---------------- T1 f32 [lb][ci=128][n=1024] -> bf16 t1B [lb][n][ci] ----------------
__global__ __launch_bounds__(256) void kt1cvt(float* __restrict__ ws) {
    __shared__ float Ld[64][65];
    unsigned short* t1B = (unsigned short*)(ws + OFF_T2);
    int bid = blockIdx.x;
    int ntile = bid & 15;
    int r = bid >> 4;
    int ct = r & 1;
    int lb = r >> 1;
    int t = threadIdx.x;
    const float* t1p = ws + OFF_T1 + (size_t)lb * HH * 1024;
    #pragma unroll
    for (int i = 0; i < 4; i++) {
        int f = t + i * 256;
        int row = f >> 4, c4 = f & 15;
        float4 v = *(const float4*)(t1p + (size_t)(ct * 64 + row) * 1024 + ntile * 64 + c4 * 4);
        *(float4*)&Ld[row][c4 * 4] = v;
    }
    __syncthreads();
    #pragma unroll
    for (int i = 0; i < 2; i++) {
        int f = t + i * 256;
        int row = f >> 3, seg = f & 7;
        unsigned int pk[4];
        #pragma unroll
        for (int e = 0; e < 4; e++) {
            unsigned int lo = f2bf(Ld[seg * 8 + 2 * e][row]);
            unsigned int hi = f2bf(Ld[seg * 8 + 2 * e + 1][row]);
            pk[e] = lo | (hi << 16);
        }
        uint4 o = make_uint4(pk[0], pk[1], pk[2], pk[3]);
        *(uint4*)(t1B + ((size_t)(lb * 1024 + ntile * 64 + row)) * HH + ct * 64 + seg * 8) = o;
    }
}

// ---------------- weight repack: lw2 f32 [l][co][ci][9] -> bf16 [l][tap][co][ci] -----
__global__ __launch_bounds__(256) void kw2cvt(const float* __restrict__ lw2, float* __restrict__ ws) {
    unsigned short* w2B = (unsigned short*)(ws + OFF_T2) + T1BSH;
    int bid = blockIdx.x;
    int l = bid / MD, co = bid % MD;
    int t = threadIdx.x;
    if (t < HH) {
        int ci = t;
        const float* src = lw2 + ((size_t)(l * MD + co) * HH + ci) * 9;
        #pragma unroll
        for (int tap = 0; tap < 9; tap++) {
            w2B[((size_t)((l * 9 + tap) * MD + co)) * HH + ci] = f2bf(src[tap]);
        }
    }
}

// ------- conv2 MFMA, split-K x2: 64co x 256n per block, 9 of 18 kc-chunks each -------
__global__ __launch_bounds__(256) void kconv2m(float* __restrict__ ws) {
    __shared__ __align__(16) unsigned short Ab[64][72];
    __shared__ __align__(16) unsigned short Bb[256][72];
    int bid = blockIdx.x;
    int s = bid & 1;
    int ntile = (bid >> 1) & 3;
    int lb = bid >> 3;
    int l = lb >> 4;
    int t = threadIdx.x;
    int lane = t & 63;
    int wave = t >> 6;
    int fr = lane & 15, fq = lane >> 4;
    const unsigned short* t1B = (const unsigned short*)(ws + OFF_T2);
    const unsigned short* w2B = (const unsigned short*)(ws + OFF_T2) + T1BSH;

    f32x4 acc[4][4];
    #pragma unroll
    for (int mi = 0; mi < 4; mi++)
        #pragma unroll
        for (int ni = 0; ni < 4; ni++) acc[mi][ni] = (f32x4){0.f, 0.f, 0.f, 0.f};

    for (int g = s * 9; g < s * 9 + 9; ++g) {
        int tap = g >> 1;
        int kc = (g & 1) * 64;
        int dy = tap / 3 - 1, dx = tap % 3 - 1;
        const unsigned short* wpl = w2B + (size_t)((l * 9 + tap) * MD) * HH;
        __syncthreads();
        #pragma unroll
        for (int i = 0; i < 2; i++) {
            int f = t + i * 256;
            int row = f >> 3, seg = f & 7;
            uint4 v = *(const uint4*)(wpl + (size_t)row * HH + kc + seg * 8);
            *(uint4*)&Ab[row][seg * 8] = v;
        }
        #pragma unroll
        for (int i = 0; i < 8; i++) {
            int f = t + i * 256;
            int row = f >> 3, seg = f & 7;
            int n = ntile * 256 + row;
            int y = (n >> 5) + dy, x = (n & 31) + dx;
            bool ok = ((unsigned)y < 32u) && ((unsigned)x < 32u);
            uint4 v = make_uint4(0u, 0u, 0u, 0u);
            if (ok) v = *(const uint4*)(t1B + ((size_t)(lb * 1024 + y * 32 + x)) * HH + kc + seg * 8);
            *(uint4*)&Bb[row][seg * 8] = v;
        }
        __syncthreads();
        #pragma unroll
        for (int kk = 0; kk < 64; kk += 32) {
            bf16x8 af[4], bfv[4];
            #pragma unroll
            for (int mi = 0; mi < 4; mi++)
                af[mi] = *(const bf16x8*)&Ab[mi * 16 + fr][kk + fq * 8];
            #pragma unroll
            for (int ni = 0; ni < 4; ni++)
                bfv[ni] = *(const bf16x8*)&Bb[wave * 64 + ni * 16 + fr][kk + fq * 8];
            #pragma unroll
            for (int mi = 0; mi < 4; mi++)
                #pragma unroll
                for (int ni = 0; ni < 4; ni++)
                    acc[mi][ni] = __builtin_amdgcn_mfma_f32_16x16x32_bf16(af[mi], bfv[ni], acc[mi][ni], 0, 0, 0);
        }
    }
    float* dst = (s == 1) ? (ws + OFF_X2 + (size_t)lb * MD * 1024)
                          : (ws + OFF_C2P + (size_t)lb * MD * 1024);
    #pragma unroll
    for (int mi = 0; mi < 4; mi++) {
        #pragma unroll
        for (int ni = 0; ni < 4; ni++) {
            int gn = ntile * 256 + wave * 64 + ni * 16 + fr;
            #pragma unroll
            for (int rr = 0; rr < 4; rr++) {
                int co = mi * 16 + fq * 4 + rr;
                dst[(size_t)co * 1024 + gn] = acc[mi][ni][rr];
            }
        }
    }
}

// ---------------- reduce conv2 partial into X2 ----------------
__global__ __launch_bounds__(256) void kc2red(float* __restrict__ ws) {
    size_t i = ((size_t)blockIdx.x * 256 + threadIdx.x) * 8;
    float4 a0 = *(float4*)(ws + OFF_X2 + i);
    float4 a1 = *(float4*)(ws + OFF_X2 + i + 4);
    const float* p = ws + OFF_C2P + i;
    float4 b0 = *(const float4*)p;
    float4 b1 = *(const float4*)(p + 4);
    a0.x += b0.x; a0.y += b0.y; a0.z += b0.z; a0.w += b0.w;
    a1.x += b1.x; a1.y += b1.y; a1.z += b1.z; a1.w += b1.w;
    *(float4*)(ws + OFF_X2 + i) = a0;
    *(float4*)(ws + OFF_X2 + i + 4) = a1;
}

// ---------------- conv3 1x1 64->2 + bias ----------------
__global__ __launch_bounds__(256) void kconv3(const float* __restrict__ lw3,
                                              const float* __restrict__ lb3,
                                              float* __restrict__ ws) {
    __shared__ float w3s[2][64];
    int bid = blockIdx.x;
    int tile = bid & 15;
    int lb = bid >> 4;
    int l = lb >> 4;
    int t = threadIdx.x;
    if (t < 128) w3s[t >> 6][t & 63] = lw3[(size_t)(l * 2 + (t >> 6)) * MD + (t & 63)];
    __syncthreads();
    const float* t2p = ws + OFF_T2 + (size_t)lb * MD * 4096;
    int hw = tile * 256 + t;
    float a0 = lb3[l * 2], a1 = lb3[l * 2 + 1];
    for (int c2 = 0; c2 < MD; c2++) {
        float v = t2p[(size_t)c2 * 4096 + hw];
        a0 += v * w3s[0][c2];
        a1 += v * w3s[1][c2];
    }
    float* r3 = ws + OFF_RAW3 + (size_t)lb * 2 * 4096;
    r3[hw] = a0;
    r3[4096 + hw] = a1;
}

// ---------------- pool 4x4 + channel softmax -> patch outputs ----------------
__global__ __launch_bounds__(256) void kpool(const float* __restrict__ ws, float* __restrict__ out) {
    int lb = blockIdx.x;
    int t = threadIdx.x;
    int gy = t >> 4, gx = t & 15;
    const float* r3 = ws + OFF_RAW3 + (size_t)lb * 2 * 4096;
    float pl[2];
    #pragma unroll
    for (int ch = 0; ch < 2; ch++) {
        const float* basep = r3 + ch * 4096;
        float s = 0.f;
        #pragma unroll
        for (int dy = 0; dy < 4; dy++)
            #pragma unroll
            for (int dx = 0; dx < 4; dx++)
                s += basep[(gy * 4 + dy) * 64 + gx * 4 + dx];
        pl[ch] = s * (1.f / 16.f);
    }
    out[O_PLG + lb * NNQ + t] = pl[1] - pl[0];
    out[O_PSC + lb * NNQ + t] = 1.f / (1.f + expf(pl[0] - pl[1]));
}

// ---------------- bilinear resize 64x64 -> 240x240 (half-pixel, clamped) -------------
__global__ __launch_bounds__(256) void kresize(const float* __restrict__ ws, float* __restrict__ out) {
    int id = blockIdx.x * 256 + threadIdx.x;
    int ox = id % IMGSZ;
    int tmp = id / IMGSZ;
    int oy = tmp % IMGSZ;
    int tmp2 = tmp / IMGSZ;
    int ch = tmp2 & 1;
    int lb = tmp2 >> 1;
    const float S = 64.f / 240.f;
    float xs = fminf(fmaxf((ox + 0.5f) * S - 0.5f, 0.f), 63.f);
    float ys = fminf(fmaxf((oy + 0.5f) * S - 0.5f, 0.f), 63.f);
    int x0 = (int)xs, y0 = (int)ys;
    float fx = xs - x0, fy = ys - y0;
    int x1 = min(x0 + 1, 63), y1 = min(y0 + 1, 63);
    const float* basep = ws + OFF_RAW3 + (size_t)(lb * 2 + ch) * 4096;
    float v00 = basep[y0 * 64 + x0], v01 = basep[y0 * 64 + x1];
    float v10 = basep[y1 * 64 + x0], v11 = basep[y1 * 64 + x1];
    float v = (1.f - fy) * ((1.f - fx) * v00 + fx * v01) + fy * ((1.f - fx) * v10 + fx * v11);
    out[O_LOC + id] = v;
}

// ---------------- GAP/GMP pooled vector (many-block, coalesced) ----------------
__global__ __launch_bounds__(256) void kgap(float* __restrict__ ws,
                                            const float* __restrict__ pool_logits) {
    int bid = blockIdx.x;
    int dchunk = bid % 12;
    int lb = bid / 12;
    int l = lb >> 4;
    int t = threadIdx.x;
    int r = t >> 2, p = t & 3;
    int d = dchunk * 64 + r;
    const float* row = ws + OFF_CMAP + (size_t)lb * DD * NNQ + (size_t)d * NNQ + p * 64;
    float s = 0.f, mx = -1e30f, mn = 1e30f;
    #pragma unroll
    for (int i = 0; i < 16; i++) {
        float4 v = *(const float4*)(row + i * 4);
        s += v.x + v.y + v.z + v.w;
        mx = fmaxf(mx, fmaxf(fmaxf(v.x, v.y), fmaxf(v.z, v.w)));
        mn = fminf(mn, fminf(fminf(v.x, v.y), fminf(v.z, v.w)));
    }
    s += __shfl_xor(s, 1, 64); s += __shfl_xor(s, 2, 64);
    mx = fmaxf(mx, __shfl_xor(mx, 1, 64)); mx = fmaxf(mx, __shfl_xor(mx, 2, 64));
    mn = fminf(mn, __shfl_xor(mn, 1, 64)); mn = fminf(mn, __shfl_xor(mn, 2, 64));
    if (p == 0) {
        float p0 = pool_logits[l * 2], p1 = pool_logits[l * 2 + 1];
        float mxp = fmaxf(p0, p1);
        float e0 = expf(p0 - mxp), e1 = expf(p1 - mxp);
        float pw0 = e0 / (e0 + e1), pw1 = e1 / (e0 + e1);
        const float* bns = ws + OFF_BNSH + l * DD;
        const float* bnb = ws + OFF_BNSH + LLY * DD + l * DD;
        float scv = bns[d], bov = bnb[d];
        float gap = scv * (s * (1.f / NNQ)) + bov;
        float gmp = (scv >= 0.f) ? (scv * mx + bov) : (scv * mn + bov);
        ws[OFF_PGL + lb * DD + d] = pw0 * gap + pw1 * gmp;
    }
}

// ---------------- global head tail: MLP + LN from pooled ----------------
__global__ __launch_bounds__(256) void kglob2(const float* __restrict__ ws,
                                              const float* __restrict__ pool_logits,
                                              const float* __restrict__ mw1,
                                              const float* __restrict__ mlng,
                                              const float* __restrict__ mlnb,
                                              const float* __restrict__ mw2,
                                              const float* __restrict__ mb2,
                                              float* __restrict__ out) {
    __shared__ float pooled[DD];
    __shared__ float zbuf[HH];
    __shared__ float hbuf[HH];
    __shared__ float sm[4];
    int lb = blockIdx.x;
    int l = lb >> 4;
    int b = lb & 15;
    int t = threadIdx.x;
    float p0 = pool_logits[l * 2], p1 = pool_logits[l * 2 + 1];
    float mx = fmaxf(p0, p1);
    float e0 = expf(p0 - mx), e1 = expf(p1 - mx);
    float pw0 = e0 / (e0 + e1), pw1 = e1 / (e0 + e1);
    if (b == 0 && t < 2) out[O_PW + l * 2 + t] = (t == 0) ? pw0 : pw1;

    for (int d = t; d < DD; d += 256) pooled[d] = ws[OFF_PGL + lb * DD + d];
    __syncthreads();
    if (t < HH) {
        const float* wrow = mw1 + (size_t)(l * HH + t) * DD;
        float a = 0.f;
        for (int d2 = 0; d2 < DD; d2++) a += pooled[d2] * wrow[d2];
        zbuf[t] = a;
    }
    __syncthreads();
    float zv = (t < HH) ? zbuf[t] : 0.f;
    float s1r = blockReduceSum(zv, sm);
    float s2r = blockReduceSum(zv * zv, sm);
    float mean = s1r * (1.f / HH);
    float var = s2r * (1.f / HH) - mean * mean;
    float rstd = rsqrtf(var + 1e-5f);
    if (t < HH) {
        float h = (zbuf[t] - mean) * rstd * mlng[l * HH + t] + mlnb[l * HH + t];
        hbuf[t] = fmaxf(h, 0.f);
    }
    __syncthreads();
    float hv = (t < HH) ? hbuf[t] : 0.f;
    float w0v = (t < HH) ? mw2[(size_t)(l * 2 + 0) * HH + t] : 0.f;
    float w1v = (t < HH) ? mw2[(size_t)(l * 2 + 1) * HH + t] : 0.f;
    float s0 = blockReduceSum(hv * w0v, sm);
    float s1 = blockReduceSum(hv * w1v, sm);
    if (t == 0) out[O_GLG + lb] = (s1 + mb2[l * 2 + 1]) - (s0 + mb2[l * 2]);
}

extern "C" void kernel_launch(void* const* d_in, const int* in_sizes, int n_in,
                              void* d_out, int out_size, void* d_ws, size_t ws_size,
                              hipStream_t stream) {
    const float* query      = (const float*)d_in[0];
    const float* prompt     = (const float*)d_in[1];
    const float* sharebn_g  = (const float*)d_in[2];
    const float* sharebn_b  = (const float*)d_in[3];
    const float* lw1        = (const float*)d_in[4];
    const float* lbn1g      = (const float*)d_in[5];
    const float* lbn1b      = (const float*)d_in[6];
    const float* lwt1       = (const float*)d_in[7];
    const float* lbt1       = (const float*)d_in[8];
    const float* lw2        = (const float*)d_in[9];
    const float* lbn2g      = (const float*)d_in[10];
    const float* lbn2b      = (const float*)d_in[11];
    const float* lwt2       = (const float*)d_in[12];
    const float* lbt2       = (const float*)d_in[13];
    const float* lw3        = (const float*)d_in[14];
    const float* lb3        = (const float*)d_in[15];
    const float* pool_logits= (const float*)d_in[16];
    const float* mw1        = (const float*)d_in[17];
    const float* mlng       = (const float*)d_in[18];
    const float* mlnb       = (const float*)d_in[19];
    const float* mw2        = (const float*)d_in[20];
    const float* mb2        = (const float*)d_in[21];
    float* out = (float*)d_out;
    float* ws = (float*)d_ws;

    hipLaunchKernelGGL(knormq, dim3(LLY*BB*NNQ), dim3(192), 0, stream, query, ws);
    hipLaunchKernelGGL(ksimm, dim3(LBTOT*16), dim3(512), 0, stream, prompt, ws);
    hipLaunchKernelGGL(kpost, dim3(LBTOT*16), dim3(256), 0, stream, query, prompt, ws, out);
    hipLaunchKernelGGL(kbnstats, dim3(LLY*DD), dim3(256), 0, stream,
                       ws + OFF_CMAP, DD, NNQ, sharebn_g, sharebn_b, ws + OFF_BNSH);
    // conv1 via MFMA, split-K x6
    hipLaunchKernelGGL(kw1cvt, dim3(LLY*HH), dim3(256), 0, stream, lw1, ws);
    hipLaunchKernelGGL(kbn1cvt, dim3(LBTOT*48), dim3(256), 0, stream, ws);
    hipLaunchKernelGGL(kconv1m, dim3(LBTOT*12), dim3(256), 0, stream, ws);
    hipLaunchKernelGGL(kc1red, dim3(768), dim3(256), 0, stream, ws);
    hipLaunchKernelGGL(kbnstats, dim3(LLY*HH), dim3(256), 0, stream,
                       ws + OFF_X1, HH, 256, lbn1g, lbn1b, ws + OFF_BN1);
    hipLaunchKernelGGL(kconvT, dim3(LBTOT*16), dim3(256), 0, stream,
                       lwt1, lbt1, ws + OFF_X1, ws + OFF_BN1, ws + OFF_T1, HH, HH, 4, 1, 4);
    // conv2 via MFMA, split-K x2
    hipLaunchKernelGGL(kt1cvt, dim3(LBTOT*32), dim3(256), 0, stream, ws);
    hipLaunchKernelGGL(kw2cvt, dim3(LLY*MD), dim3(256), 0, stream, lw2, ws);
    hipLaunchKernelGGL(kconv2m, dim3(LBTOT*8), dim3(256), 0, stream, ws);
    hipLaunchKernelGGL(kc2red, dim3(1536), dim3(256), 0, stream, ws);
    hipLaunchKernelGGL(kbnstats, dim3(LLY*MD), dim3(256), 0, stream,
                       ws + OFF_X2, MD, 1024, lbn2g, lbn2b, ws + OFF_BN2);
    hipLaunchKernelGGL(kconvT, dim3(LBTOT*32), dim3(256), 0, stream,
                       lwt2, lbt2, ws + OFF_X2, ws + OFF_BN2, ws + OFF_T2, MD, MD, 5, 4, 2);
    hipLaunchKernelGGL(kconv3, dim3(LBTOT*16), dim3(256), 0, stream, lw3, lb3, ws);
    hipLaunchKernelGGL(kpool, dim3(LBTOT), dim3(256), 0, stream, ws, out);
    hipLaunchKernelGGL(kresize, dim3(LLY*BB*2*IMGSZ*IMGSZ/256), dim3(256), 0, stream, ws, out);
    hipLaunchKernelGGL(kgap, dim3(LBTOT*12), dim3(256), 0, stream, ws, pool_logits);
    hipLaunchKernelGGL(kglob2, dim3(LBTOT), dim3(256), 0, stream,
                       ws, pool_logits, mw1, mlng, mlnb, mw2, mb2, out);
}

// Round 11
// 516.608 us; speedup vs baseline: 1.1010x; 1.0275x over previous
//
#include <hip/hip_runtime.h>
#include <hip/hip_bf16.h>
#include <math.h>

#define LLY 3
#define BB 16
#define NNQ 256
#define DD 768
#define MMP 2048
#define HH 128
#define MD 64
#define IMGSZ 240
#define LBTOT (LLY*BB)

// ---------------- workspace layout (floats) ----------------
#define OFF_INVQ 0
#define OFF_INVP (OFF_INVQ + LLY*BB*NNQ)
#define OFF_CMAP (OFF_INVP + LLY*BB*MMP)
#define OFF_BNSH (OFF_CMAP + LLY*BB*DD*NNQ)
#define OFF_X1   (OFF_BNSH + 2*LLY*DD)
#define OFF_BN1  (OFF_X1 + LLY*BB*HH*256)
#define OFF_T1   (OFF_BN1 + 2*LLY*HH)
#define OFF_X2   (OFF_T1 + LLY*BB*HH*1024)
#define OFF_BN2  (OFF_X2 + LLY*BB*MD*1024)
#define OFF_T2   (OFF_BN2 + 2*LLY*MD)
#define OFF_RAW3 (OFF_T2 + LLY*BB*MD*4096)
#define WS_FLOATS (OFF_RAW3 + LLY*BB*2*4096)
#define T1BSH (LBTOT*1024*HH)      // shorts
#define SQH   (LBTOT*NNQ*DD)       // shorts per q-split plane
#define OFF_C1P (OFF_T2 + 4718592)
#define OFF_C2P (OFF_T2 + 3256320)
#define OFF_PGL OFF_X1
// transient bf16 scratch (time-multiplexed):
//   x1b  (bf16 [lb][256][128])  T2 shorts [0, 1572864)      (cmT dead after kc1red)
//   wt1b (bf16 [l][4][128][128])T2 shorts [1600000, 1796608)
//   t1B  overwrites x1b/wt1b after convT1m
//   x2b  (bf16 [lb][1024][64])  X1 region (exact fit, dead after kpost/convT1 chain)
//   wt2b (bf16 [l][4][64][64])  X2 region start (X2 fully read before kwtcvt2)
#define X1B_SH 0
#define WT1B_SH 1600000

// ---------------- output layout (floats) ----------------
#define O_RES 0
#define O_PSC (O_RES + LLY*BB*NNQ)
#define O_PLG (O_PSC + LLY*BB*NNQ)
#define O_GLG (O_PLG + LLY*BB*NNQ)
#define O_LOC (O_GLG + LLY*BB)
#define O_PW  (O_LOC + LLY*BB*2*IMGSZ*IMGSZ)
#define O_IDX (O_PW + LLY*2)
#define O_ALN (O_IDX + LLY*BB*NNQ)

typedef __attribute__((ext_vector_type(8))) short bf16x8;
typedef __attribute__((ext_vector_type(4))) float f32x4;

__device__ __forceinline__ unsigned short f2bf(float f) {
    __hip_bfloat16 h = __float2bfloat16(f);
    unsigned short u;
    __builtin_memcpy(&u, &h, sizeof(u));
    return u;
}
__device__ __forceinline__ float bf2f(unsigned short h) {
    return __uint_as_float(((unsigned int)h) << 16);
}

__device__ __forceinline__ float blockReduceSum(float v, float* sm) {
    for (int o = 32; o; o >>= 1) v += __shfl_down(v, o, 64);
    __syncthreads();
    if ((threadIdx.x & 63) == 0) sm[threadIdx.x >> 6] = v;
    __syncthreads();
    return sm[0] + sm[1] + sm[2] + sm[3];
}

// ------- fused: query row L2-norm + normalized bf16 hi/lo split (into T2 region) -----
__global__ __launch_bounds__(192) void knormq(const float* __restrict__ query,
                                              float* __restrict__ ws) {
    __shared__ float sm[3];
    int row = blockIdx.x;
    int t = threadIdx.x;
    float4 v = *(const float4*)(query + (size_t)row * DD + t * 4);
    float ss = v.x * v.x + v.y * v.y + v.z * v.z + v.w * v.w;
    for (int o = 32; o; o >>= 1) ss += __shfl_down(ss, o, 64);
    if ((t & 63) == 0) sm[t >> 6] = ss;
    __syncthreads();
    ss = sm[0] + sm[1] + sm[2];
    float iv = 1.0f / fmaxf(sqrtf(ss), 1e-12f);
    if (t == 0) ws[OFF_INVQ + row] = iv;
    unsigned short* qh = (unsigned short*)(ws + OFF_T2);
    unsigned short* ql = qh + SQH;
    float e[4] = {v.x * iv, v.y * iv, v.z * iv, v.w * iv};
    unsigned int hp[2], lp[2];
    #pragma unroll
    for (int j = 0; j < 2; j++) {
        unsigned short h0 = f2bf(e[2*j]), h1 = f2bf(e[2*j+1]);
        unsigned short l0 = f2bf(e[2*j] - bf2f(h0)), l1 = f2bf(e[2*j+1] - bf2f(h1));
        hp[j] = (unsigned int)h0 | ((unsigned int)h1 << 16);
        lp[j] = (unsigned int)l0 | ((unsigned int)l1 << 16);
    }
    *(uint2*)(qh + (size_t)row * DD + t * 4) = make_uint2(hp[0], hp[1]);
    *(uint2*)(ql + (size_t)row * DD + t * 4) = make_uint2(lp[0], lp[1]);
}

// ---- sim GEMM: 128p x 256q block, 8 waves of 64x64, fused p-norm, 40-short stride ---
__global__ __launch_bounds__(512) void ksimm(const float* __restrict__ prompt, float* __restrict__ ws) {
    __shared__ __align__(16) unsigned short Ah[128][40];
    __shared__ __align__(16) unsigned short Al[128][40];
    __shared__ __align__(16) unsigned short Bh[256][40];
    __shared__ __align__(16) unsigned short Bl[256][40];
    __shared__ float invL[128];
    int bid = blockIdx.x;
    int mt = bid & 15;
    int lb = bid >> 4;
    int t = threadIdx.x;
    int lane = t & 63, wave = t >> 6;
    int wm = wave >> 2, wn = wave & 3;
    int fr = lane & 15, fq = lane >> 4;
    const unsigned short* qh = (const unsigned short*)(ws + OFF_T2);
    const unsigned short* ql = qh + SQH;
    const float* pbase = prompt + (size_t)lb * MMP * DD + (size_t)(mt * 128) * DD;

    float ssq[2] = {0.f, 0.f};

    f32x4 acc[4][4];
    #pragma unroll
    for (int mi = 0; mi < 4; mi++)
        #pragma unroll
        for (int ni = 0; ni < 4; ni++) acc[mi][ni] = (f32x4){0.f, 0.f, 0.f, 0.f};

    for (int kc = 0; kc < DD; kc += 32) {
        __syncthreads();
        #pragma unroll
        for (int i = 0; i < 2; i++) {          // stage P: 128 x 32 f32 -> hi/lo (+ssq)
            int f = t + i * 512;
            int row = f >> 3, c4 = f & 7;
            float4 v = *(const float4*)(pbase + (size_t)row * DD + kc + c4 * 4);
            ssq[i] += v.x * v.x + v.y * v.y + v.z * v.z + v.w * v.w;
            unsigned short h0 = f2bf(v.x), h1 = f2bf(v.y), h2 = f2bf(v.z), h3 = f2bf(v.w);
            unsigned short l0 = f2bf(v.x - bf2f(h0)), l1 = f2bf(v.y - bf2f(h1));
            unsigned short l2 = f2bf(v.z - bf2f(h2)), l3 = f2bf(v.w - bf2f(h3));
            uint2 hp = make_uint2((unsigned int)h0 | ((unsigned int)h1 << 16),
                                  (unsigned int)h2 | ((unsigned int)h3 << 16));
            uint2 lp = make_uint2((unsigned int)l0 | ((unsigned int)l1 << 16),
                                  (unsigned int)l2 | ((unsigned int)l3 << 16));
            *(uint2*)&Ah[row][c4 * 4] = hp;
            *(uint2*)&Al[row][c4 * 4] = lp;
        }
        #pragma unroll
        for (int i = 0; i < 2; i++) {          // stage Q: 256 x 32 bf16 hi/lo
            int f = t + i * 512;
            int row = f >> 2, sg = f & 3;
            size_t go = (size_t)(lb * NNQ + row) * DD + kc + sg * 8;
            *(uint4*)&Bh[row][sg * 8] = *(const uint4*)(qh + go);
            *(uint4*)&Bl[row][sg * 8] = *(const uint4*)(ql + go);
        }
        __syncthreads();
        bf16x8 ah[4], al4[4], bh[4], bl4[4];
        #pragma unroll
        for (int mi = 0; mi < 4; mi++) {
            ah[mi]  = *(const bf16x8*)&Ah[wm * 64 + mi * 16 + fr][fq * 8];
            al4[mi] = *(const bf16x8*)&Al[wm * 64 + mi * 16 + fr][fq * 8];
        }
        #pragma unroll
        for (int ni = 0; ni < 4; ni++) {
            bh[ni]  = *(const bf16x8*)&Bh[wn * 64 + ni * 16 + fr][fq * 8];
            bl4[ni] = *(const bf16x8*)&Bl[wn * 64 + ni * 16 + fr][fq * 8];
        }
        #pragma unroll
        for (int mi = 0; mi < 4; mi++)
            #pragma unroll
            for (int ni = 0; ni < 4; ni++) {
                acc[mi][ni] = __builtin_amdgcn_mfma_f32_16x16x32_bf16(ah[mi],  bh[ni],  acc[mi][ni], 0, 0, 0);
                acc[mi][ni] = __builtin_amdgcn_mfma_f32_16x16x32_bf16(ah[mi],  bl4[ni], acc[mi][ni], 0, 0, 0);
                acc[mi][ni] = __builtin_amdgcn_mfma_f32_16x16x32_bf16(al4[mi], bh[ni],  acc[mi][ni], 0, 0, 0);
            }
    }
    // prompt norms: reduce ssq across the 8 staging lanes per row
    #pragma unroll
    for (int i = 0; i < 2; i++) {
        float s = ssq[i];
        s += __shfl_xor(s, 1, 64);
        s += __shfl_xor(s, 2, 64);
        s += __shfl_xor(s, 4, 64);
        if ((t & 7) == 0) {
            int row = (t >> 3) + 64 * i;
            float iv = 1.0f / fmaxf(sqrtf(s), 1e-12f);
            invL[row] = iv;
            ws[OFF_INVP + lb * MMP + mt * 128 + row] = iv;
        }
    }
    __syncthreads();
    // fold invp + per-wave argmax over 64 prompts (ascending m within wave)
    float* bestv = ws + OFF_X1;
    float* besti = ws + OFF_X1 + (size_t)LBTOT * NNQ * 32;
    #pragma unroll
    for (int ni = 0; ni < 4; ni++) {
        float bv = -1e30f; int bi = 0;
        #pragma unroll
        for (int mi = 0; mi < 4; mi++)
            #pragma unroll
            for (int rr = 0; rr < 4; rr++) {
                int lm = wm * 64 + mi * 16 + fq * 4 + rr;
                float s = acc[mi][ni][rr] * invL[lm];
                int m = mt * 128 + lm;
                if (s > bv) { bv = s; bi = m; }
            }
        #pragma unroll
        for (int o = 16; o <= 32; o <<= 1) {
            float ov = __shfl_xor(bv, o, 64);
            int oi = __shfl_xor(bi, o, 64);
            if (ov > bv || (ov == bv && oi < bi)) { bv = ov; bi = oi; }
        }
        if (fq == 0) {
            int q = wn * 64 + ni * 16 + fr;
            size_t slot = (size_t)(lb * NNQ + q) * 32 + wm * 16 + mt;
            bestv[slot] = bv;
            besti[slot] = (float)bi;
        }
    }
}

// --- argmax finalize + residual/idx/aligned/ctx; cmap written via LDS transpose ------
__global__ __launch_bounds__(256) void kpost(const float* __restrict__ query,
                                             const float* __restrict__ prompt,
                                             float* __restrict__ ws,
                                             float* __restrict__ out) {
    __shared__ float red_v[16];
    __shared__ int   red_i[16];
    __shared__ float Lctx[DD * 17];
    int bid = blockIdx.x;
    int nt = bid & 15;
    int lb = bid >> 4;
    int t = threadIdx.x;
    const float* bestv = ws + OFF_X1;
    const float* besti = ws + OFF_X1 + (size_t)LBTOT * NNQ * 32;
    if (t < 16) {
        int q = nt * 16 + t;
        const float* bv = bestv + (size_t)(lb * NNQ + q) * 32;
        const float* bi = besti + (size_t)(lb * NNQ + q) * 32;
        float best = -1e30f; int bidx2 = 0;
        for (int mtt = 0; mtt < 16; mtt++)
            #pragma unroll
            for (int wm = 0; wm < 2; wm++) {
                float v = bv[wm * 16 + mtt];
                if (v > best) { best = v; bidx2 = (int)bi[wm * 16 + mtt]; }
            }
        red_v[t] = best; red_i[t] = bidx2;
        out[O_RES + lb * NNQ + q] = 0.5f * (1.0f - best);
        out[O_IDX + lb * NNQ + q] = (float)bidx2;
    }
    __syncthreads();
    const float* qbase = query + (size_t)(lb * NNQ + nt * 16) * DD;
    const float* pbase = prompt + (size_t)lb * MMP * DD;
    const float* invq = ws + OFF_INVQ + lb * NNQ + nt * 16;
    const float* invp = ws + OFF_INVP + lb * MMP;
    int c = t & 15;
    int nn = t >> 4;
    int gn = nt * 16 + nn;
    int midx = red_i[nn];
    float ip = invp[midx];
    float iq = invq[nn];
    const float* prow = pbase + (size_t)midx * DD;
    const float* qrow = qbase + (size_t)nn * DD;
    float* aln = out + O_ALN + (size_t)(lb * NNQ + gn) * DD;
    for (int jj = 0; jj < DD / 16; jj++) {
        int d = c + jj * 16;
        float pvr = prow[d];
        float qv = qrow[d] * iq;
        float av = pvr * ip;
        float cx = qv + fabsf(qv - av);
        aln[d] = pvr;
        Lctx[d * 17 + nn] = cx;
    }
    __syncthreads();
    float* cm = ws + OFF_CMAP + (size_t)lb * DD * NNQ + nt * 16;
    int nl = t & 15, dd = t >> 4;
    for (int jj = 0; jj < DD / 16; jj++) {
        int d = jj * 16 + dd;
        cm[(size_t)d * NNQ + nl] = Lctx[d * 17 + nl];
    }
}

// ---------------- BN batch stats (per l,c over B x SP), biased var ----------------
__global__ __launch_bounds__(256) void kbnstats(const float* __restrict__ x, int C, int SP,
                                                const float* __restrict__ g,
                                                const float* __restrict__ b,
                                                float* __restrict__ outSB) {
    __shared__ float sm[4];
    int bid = blockIdx.x;
    int c = bid % C;
    int l = bid / C;
    int t = threadIdx.x;
    float s = 0.f, sq = 0.f;
    for (int bb2 = 0; bb2 < BB; ++bb2) {
        const float* p = x + ((size_t)(l * BB + bb2) * C + c) * SP;
        for (int i = t; i < SP; i += 256) { float v = p[i]; s += v; sq += v * v; }
    }
    s = blockReduceSum(s, sm);
    sq = blockReduceSum(sq, sm);
    if (t == 0) {
        float inv = 1.0f / (float)(BB * SP);
        float m = s * inv;
        float var = sq * inv - m * m;
        float sc = g[l * C + c] * rsqrtf(var + 1e-5f);
        float bo = b[l * C + c] - m * sc;
        outSB[l * C + c] = sc;
        outSB[LLY * C + l * C + c] = bo;
    }
}

// ---------------- weight repack: lw1 f32 [l][co][ci][9] -> bf16 [l][tap][co][ci] -----
__global__ __launch_bounds__(256) void kw1cvt(const float* __restrict__ lw1, float* __restrict__ ws) {
    unsigned short* w1B = (unsigned short*)(ws + OFF_X2);
    int bid = blockIdx.x;
    int l = bid / HH, co = bid % HH;
    int t = threadIdx.x;
    for (int c0 = 0; c0 < DD; c0 += 256) {
        int ci = c0 + t;
        const float* src = lw1 + ((size_t)(l * HH + co) * DD + ci) * 9;
        #pragma unroll
        for (int tap = 0; tap < 9; tap++) {
            w1B[((size_t)((l * 9 + tap) * HH + co)) * DD + ci] = f2bf(src[tap]);
        }
    }
}

// ---------------- BN-fold + transpose: cmap f32 [lb][ci][n] -> bf16 cmT [lb][n][ci] --
__global__ __launch_bounds__(256) void kbn1cvt(float* __restrict__ ws) {
    __shared__ float Ld[64][65];
    unsigned short* cmT = (unsigned short*)(ws + OFF_T2);
    int bid = blockIdx.x;
    int nt = bid & 3;
    int r = bid >> 2;
    int ct = r % 12;
    int lb = r / 12;
    int l = lb >> 4;
    int t = threadIdx.x;
    const float* cmap = ws + OFF_CMAP + (size_t)lb * DD * NNQ;
    const float* bns = ws + OFF_BNSH + l * DD;
    const float* bnb = ws + OFF_BNSH + LLY * DD + l * DD;
    #pragma unroll
    for (int i = 0; i < 4; i++) {
        int f = t + i * 256;
        int row = f >> 4, c4 = f & 15;
        int ci = ct * 64 + row;
        float4 v = *(const float4*)(cmap + (size_t)ci * NNQ + nt * 64 + c4 * 4);
        float s = bns[ci], bo = bnb[ci];
        Ld[row][c4*4+0] = v.x * s + bo; Ld[row][c4*4+1] = v.y * s + bo;
        Ld[row][c4*4+2] = v.z * s + bo; Ld[row][c4*4+3] = v.w * s + bo;
    }
    __syncthreads();
    #pragma unroll
    for (int i = 0; i < 2; i++) {
        int f = t + i * 256;
        int row = f >> 3, seg = f & 7;
        unsigned int pk[4];
        #pragma unroll
        for (int e = 0; e < 4; e++) {
            unsigned int lo = f2bf(Ld[seg * 8 + 2 * e][row]);
            unsigned int hi = f2bf(Ld[seg * 8 + 2 * e + 1][row]);
            pk[e] = lo | (hi << 16);
        }
        uint4 o = make_uint4(pk[0], pk[1], pk[2], pk[3]);
        *(uint4*)(cmT + ((size_t)(lb * NNQ + nt * 64 + row)) * DD + ct * 64 + seg * 8) = o;
    }
}

// ------- conv1 MFMA, split-K x6: 128co x 128n per block, 18 of 108 kc-chunks each ----
__global__ __launch_bounds__(256) void kconv1m(float* __restrict__ ws) {
    __shared__ __align__(16) unsigned short Ab[128][72];
    __shared__ __align__(16) unsigned short Bb[128][72];
    int bid = blockIdx.x;
    int s = bid % 6;
    int ntile = (bid / 6) & 1;
    int lb = bid / 12;
    int l = lb >> 4;
    int t = threadIdx.x;
    int lane = t & 63;
    int wave = t >> 6;
    int wr = wave >> 1, wc = wave & 1;
    int fr = lane & 15, fq = lane >> 4;
    const unsigned short* w1B = (const unsigned short*)(ws + OFF_X2);
    const unsigned short* cmT = (const unsigned short*)(ws + OFF_T2);

    f32x4 acc[4][4];
    #pragma unroll
    for (int mi = 0; mi < 4; mi++)
        #pragma unroll
        for (int ni = 0; ni < 4; ni++) acc[mi][ni] = (f32x4){0.f, 0.f, 0.f, 0.f};

    for (int g = s * 18; g < s * 18 + 18; ++g) {
        int tap = g / 12;
        int kc = (g % 12) * 64;
        int dy = tap / 3 - 1, dx = tap % 3 - 1;
        const unsigned short* wpl = w1B + (size_t)((l * 9 + tap) * HH) * DD;
        __syncthreads();
        #pragma unroll
        for (int i = 0; i < 4; i++) {
            int f = t + i * 256;
            int row = f >> 3, seg = f & 7;
            uint4 v = *(const uint4*)(wpl + (size_t)row * DD + kc + seg * 8);
            *(uint4*)&Ab[row][seg * 8] = v;
        }
        #pragma unroll
        for (int i = 0; i < 4; i++) {
            int f = t + i * 256;
            int row = f >> 3, seg = f & 7;
            int n = ntile * 128 + row;
            int y = (n >> 4) + dy, x = (n & 15) + dx;
            bool ok = ((unsigned)y < 16u) && ((unsigned)x < 16u);
            uint4 v = make_uint4(0u, 0u, 0u, 0u);
            if (ok) v = *(const uint4*)(cmT + ((size_t)(lb * NNQ + y * 16 + x)) * DD + kc + seg * 8);
            *(uint4*)&Bb[row][seg * 8] = v;
        }
        __syncthreads();
        #pragma unroll
        for (int kk = 0; kk < 64; kk += 32) {
            bf16x8 af[4], bfv[4];
            #pragma unroll
            for (int mi = 0; mi < 4; mi++)
                af[mi] = *(const bf16x8*)&Ab[wr * 64 + mi * 16 + fr][kk + fq * 8];
            #pragma unroll
            for (int ni = 0; ni < 4; ni++)
                bfv[ni] = *(const bf16x8*)&Bb[wc * 64 + ni * 16 + fr][kk + fq * 8];
            #pragma unroll
            for (int mi = 0; mi < 4; mi++)
                #pragma unroll
                for (int ni = 0; ni < 4; ni++)
                    acc[mi][ni] = __builtin_amdgcn_mfma_f32_16x16x32_bf16(af[mi], bfv[ni], acc[mi][ni], 0, 0, 0);
        }
    }
    float* dst = (s == 5) ? (ws + OFF_X1 + (size_t)lb * HH * 256)
                          : (ws + OFF_C1P + (size_t)(s * LBTOT + lb) * (HH * 256));
    #pragma unroll
    for (int mi = 0; mi < 4; mi++) {
        #pragma unroll
        for (int ni = 0; ni < 4; ni++) {
            int gn = ntile * 128 + wc * 64 + ni * 16 + fr;
            #pragma unroll
            for (int rr = 0; rr < 4; rr++) {
                int co = wr * 64 + mi * 16 + fq * 4 + rr;
                dst[(size_t)co * 256 + gn] = acc[mi][ni][rr];
            }
        }
    }
}

// ---------------- reduce conv1 partials into X1 ----------------
__global__ __launch_bounds__(256) void kc1red(float* __restrict__ ws) {
    size_t i = ((size_t)blockIdx.x * 256 + threadIdx.x) * 8;
    float4 a0 = *(float4*)(ws + OFF_X1 + i);
    float4 a1 = *(float4*)(ws + OFF_X1 + i + 4);
    #pragma unroll
    for (int s = 0; s < 5; s++) {
        const float* p = ws + OFF_C1P + (size_t)s * (LBTOT * HH * 256) + i;
        float4 b0 = *(const float4*)p;
        float4 b1 = *(const float4*)(p + 4);
        a0.x += b0.x; a0.y += b0.y; a0.z += b0.z; a0.w += b0.w;
        a1.x += b1.x; a1.y += b1.y; a1.z += b1.z; a1.w += b1.w;
    }
    *(float4*)(ws + OFF_X1 + i) = a0;
    *(float4*)(ws + OFF_X1 + i + 4) = a1;
}

// ---- generic: x f32 [lb][CI][SPIN] --BN+ReLU--> xb bf16 [lb][SPIN][CI] (transpose) --
__global__ __launch_bounds__(256) void kxcvt(const float* __restrict__ x,
                                             const float* __restrict__ sbsb,
                                             unsigned short* __restrict__ xb,
                                             int CI, int SPIN, int nT, int cT) {
    __shared__ float Ld[64][65];
    int bid = blockIdx.x;
    int nt = bid % nT;
    int r = bid / nT;
    int ct = r % cT;
    int lb = r / cT;
    int l = lb >> 4;
    int t = threadIdx.x;
    const float* sc = sbsb + l * CI;
    const float* bo = sbsb + LLY * CI + l * CI;
    #pragma unroll
    for (int i = 0; i < 4; i++) {
        int f = t + i * 256;
        int row = f >> 4, c4 = f & 15;
        int ci = ct * 64 + row;
        float4 v = *(const float4*)(x + ((size_t)lb * CI + ci) * SPIN + nt * 64 + c4 * 4);
        float s = sc[ci], b_ = bo[ci];
        Ld[row][c4*4+0] = fmaxf(v.x * s + b_, 0.f);
        Ld[row][c4*4+1] = fmaxf(v.y * s + b_, 0.f);
        Ld[row][c4*4+2] = fmaxf(v.z * s + b_, 0.f);
        Ld[row][c4*4+3] = fmaxf(v.w * s + b_, 0.f);
    }
    __syncthreads();
    int segs = CI >> 3;   // 8-wide ci segments per row
    for (int f = t; f < 64 * segs; f += 256) {
        int row = f / segs, seg = f % segs;
        int sl = seg - ct * 8;           // local seg within this 64-ci chunk
        if (sl < 0 || sl >= 8) continue;
        unsigned int pk[4];
        #pragma unroll
        for (int e = 0; e < 4; e++) {
            unsigned int lo = f2bf(Ld[sl * 8 + 2 * e][row]);
            unsigned int hi = f2bf(Ld[sl * 8 + 2 * e + 1][row]);
            pk[e] = lo | (hi << 16);
        }
        uint4 o = make_uint4(pk[0], pk[1], pk[2], pk[3]);
        *(uint4*)(xb + ((size_t)lb * SPIN + nt * 64 + row) * CI + ct * 64 + sl * 8) = o;
    }
}

// ---- convT weight repack: lwt f32 [l][ci][co][2][2] -> bf16 [l][pq][co][ci] ---------
__global__ __launch_bounds__(128) void kwtcvt(const float* __restrict__ lwt,
                                              unsigned short* __restrict__ dst,
                                              int CI, int CO) {
    int bid = blockIdx.x;
    int l = bid / CO, co = bid % CO;
    int t = threadIdx.x;
    if (t < CI) {
        const float* src = lwt + (((size_t)(l * CI + t) * CO + co) * 4);
        #pragma unroll
        for (int pq = 0; pq < 4; pq++) {
            dst[((size_t)((l * 4 + pq) * CO + co)) * CI + t] = f2bf(src[pq]);
        }
    }
}

// ---- convT as 4 per-pq MFMA GEMMs: 64co x 256n block, K=CI, upsample-scatter out ----
__global__ __launch_bounds__(256) void kconvTm(const unsigned short* __restrict__ xb,
                                               const unsigned short* __restrict__ wtb,
                                               const float* __restrict__ bt,
                                               float* __restrict__ xout,
                                               int CI, int CO, int gsh, int nTiles, int coTiles) {
    __shared__ __align__(16) unsigned short Ab[64][72];
    __shared__ __align__(16) unsigned short Bb[256][72];
    int bid = blockIdx.x;
    int ntile = bid % nTiles;
    int r = bid / nTiles;
    int cot = r % coTiles; r /= coTiles;
    int pq = r & 3;
    int lb = r >> 2;
    int l = lb >> 4;
    int SPIN = 1 << (2 * gsh);
    int t = threadIdx.x, lane = t & 63, wave = t >> 6;
    int fr = lane & 15, fq = lane >> 4;

    f32x4 acc[4][4];
    #pragma unroll
    for (int mi = 0; mi < 4; mi++)
        #pragma unroll
        for (int ni = 0; ni < 4; ni++) acc[mi][ni] = (f32x4){0.f, 0.f, 0.f, 0.f};

    for (int kc = 0; kc < CI; kc += 64) {
        __syncthreads();
        #pragma unroll
        for (int i = 0; i < 2; i++) {       // stage A: 64co x 64k
            int f = t + i * 256;
            int row = f >> 3, seg = f & 7;
            *(uint4*)&Ab[row][seg * 8] =
                *(const uint4*)(wtb + ((size_t)((l * 4 + pq) * CO + cot * 64 + row)) * CI + kc + seg * 8);
        }
        #pragma unroll
        for (int i = 0; i < 8; i++) {       // stage B: 256n x 64k
            int f = t + i * 256;
            int row = f >> 3, seg = f & 7;
            *(uint4*)&Bb[row][seg * 8] =
                *(const uint4*)(xb + ((size_t)lb * SPIN + ntile * 256 + row) * CI + kc + seg * 8);
        }
        __syncthreads();
        #pragma unroll
        for (int kk = 0; kk < 64; kk += 32) {
            bf16x8 af[4], bfv[4];
            #pragma unroll
            for (int mi = 0; mi < 4; mi++)
                af[mi] = *(const bf16x8*)&Ab[mi * 16 + fr][kk + fq * 8];
            #pragma unroll
            for (int ni = 0; ni < 4; ni++)
                bfv[ni] = *(const bf16x8*)&Bb[wave * 64 + ni * 16 + fr][kk + fq * 8];
            #pragma unroll
            for (int mi = 0; mi < 4; mi++)
                #pragma unroll
                for (int ni = 0; ni < 4; ni++)
                    acc[mi][ni] = __builtin_amdgcn_mfma_f32_16x16x32_bf16(af[mi], bfv[ni], acc[mi][ni], 0, 0, 0);
        }
    }
    int p = pq >> 1, q = pq & 1;
    int GIN = 1 << gsh;
    #pragma unroll
    for (int mi = 0; mi < 4; mi++) {
        #pragma unroll
        for (int rr = 0; rr < 4; rr++) {
            int co = cot * 64 + mi * 16 + fq * 4 + rr;
            float bias = bt[l * CO + co];
            float* orow = xout + ((size_t)(lb * CO + co)) * (4 * SPIN);
            #pragma unroll
            for (int ni = 0; ni < 4; ni++) {
                int n = ntile * 256 + wave * 64 + ni * 16 + fr;
                int h = n >> gsh, w = n & (GIN - 1);
                orow[(2 * h + p) * (2 * GIN) + 2 * w + q] = acc[mi][ni][rr] + bias;
            }
        }
    }
}

// ---------------- T1 f32 [lb][ci=128][n=1024] -> bf16 t1B [lb][n][ci] ----------------
__global__ __launch_bounds__(256) void kt1cvt(float* __restrict__ ws) {
    __shared__ float Ld[64][65];
    unsigned short* t1B = (unsigned short*)(ws + OFF_T2);
    int bid = blockIdx.x;
    int ntile = bid & 15;
    int r = bid >> 4;
    int ct = r & 1;
    int lb = r >> 1;
    int t = threadIdx.x;
    const float* t1p = ws + OFF_T1 + (size_t)lb * HH * 1024;
    #pragma unroll
    for (int i = 0; i < 4; i++) {
        int f = t + i * 256;
        int row = f >> 4, c4 = f & 15;
        float4 v = *(const float4*)(t1p + (size_t)(ct * 64 + row) * 1024 + ntile * 64 + c4 * 4);
        *(float4*)&Ld[row][c4 * 4] = v;
    }
    __syncthreads();
    #pragma unroll
    for (int i = 0; i < 2; i++) {
        int f = t + i * 256;
        int row = f >> 3, seg = f & 7;
        unsigned int pk[4];
        #pragma unroll
        for (int e = 0; e < 4; e++) {
            unsigned int lo = f2bf(Ld[seg * 8 + 2 * e][row]);
            unsigned int hi = f2bf(Ld[seg * 8 + 2 * e + 1][row]);
            pk[e] = lo | (hi << 16);
        }
        uint4 o = make_uint4(pk[0], pk[1], pk[2], pk[3]);
        *(uint4*)(t1B + ((size_t)(lb * 1024 + ntile * 64 + row)) * HH + ct * 64 + seg * 8) = o;
    }
}

// ---------------- weight repack: lw2 f32 [l][co][ci][9] -> bf16 [l][tap][co][ci] -----
__global__ __launch_bounds__(256) void kw2cvt(const float* __restrict__ lw2, float* __restrict__ ws) {
    unsigned short* w2B = (unsigned short*)(ws + OFF_T2) + T1BSH;
    int bid = blockIdx.x;
    int l = bid / MD, co = bid % MD;
    int t = threadIdx.x;
    if (t < HH) {
        int ci = t;
        const float* src = lw2 + ((size_t)(l * MD + co) * HH + ci) * 9;
        #pragma unroll
        for (int tap = 0; tap < 9; tap++) {
            w2B[((size_t)((l * 9 + tap) * MD + co)) * HH + ci] = f2bf(src[tap]);
        }
    }
}

// ------- conv2 MFMA, split-K x2: 64co x 256n per block, 9 of 18 kc-chunks each -------
__global__ __launch_bounds__(256) void kconv2m(float* __restrict__ ws) {
    __shared__ __align__(16) unsigned short Ab[64][72];
    __shared__ __align__(16) unsigned short Bb[256][72];
    int bid = blockIdx.x;
    int s = bid & 1;
    int ntile = (bid >> 1) & 3;
    int lb = bid >> 3;
    int l = lb >> 4;
    int t = threadIdx.x;
    int lane = t & 63;
    int wave = t >> 6;
    int fr = lane & 15, fq = lane >> 4;
    const unsigned short* t1B = (const unsigned short*)(ws + OFF_T2);
    const unsigned short* w2B = (const unsigned short*)(ws + OFF_T2) + T1BSH;

    f32x4 acc[4][4];
    #pragma unroll
    for (int mi = 0; mi < 4; mi++)
        #pragma unroll
        for (int ni = 0; ni < 4; ni++) acc[mi][ni] = (f32x4){0.f, 0.f, 0.f, 0.f};

    for (int g = s * 9; g < s * 9 + 9; ++g) {
        int tap = g >> 1;
        int kc = (g & 1) * 64;
        int dy = tap / 3 - 1, dx = tap % 3 - 1;
        const unsigned short* wpl = w2B + (size_t)((l * 9 + tap) * MD) * HH;
        __syncthreads();
        #pragma unroll
        for (int i = 0; i < 2; i++) {
            int f = t + i * 256;
            int row = f >> 3, seg = f & 7;
            uint4 v = *(const uint4*)(wpl + (size_t)row * HH + kc + seg * 8);
            *(uint4*)&Ab[row][seg * 8] = v;
        }
        #pragma unroll
        for (int i = 0; i < 8; i++) {
            int f = t + i * 256;
            int row = f >> 3, seg = f & 7;
            int n = ntile * 256 + row;
            int y = (n >> 5) + dy, x = (n & 31) + dx;
            bool ok = ((unsigned)y < 32u) && ((unsigned)x < 32u);
            uint4 v = make_uint4(0u, 0u, 0u, 0u);
            if (ok) v = *(const uint4*)(t1B + ((size_t)(lb * 1024 + y * 32 + x)) * HH + kc + seg * 8);
            *(uint4*)&Bb[row][seg * 8] = v;
        }
        __syncthreads();
        #pragma unroll
        for (int kk = 0; kk < 64; kk += 32) {
            bf16x8 af[4], bfv[4];
            #pragma unroll
            for (int mi = 0; mi < 4; mi++)
                af[mi] = *(const bf16x8*)&Ab[mi * 16 + fr][kk + fq * 8];
            #pragma unroll
            for (int ni = 0; ni < 4; ni++)
                bfv[ni] = *(const bf16x8*)&Bb[wave * 64 + ni * 16 + fr][kk + fq * 8];
            #pragma unroll
            for (int mi = 0; mi < 4; mi++)
                #pragma unroll
                for (int ni = 0; ni < 4; ni++)
                    acc[mi][ni] = __builtin_amdgcn_mfma_f32_16x16x32_bf16(af[mi], bfv[ni], acc[mi][ni], 0, 0, 0);
        }
    }
    float* dst = (s == 1) ? (ws + OFF_X2 + (size_t)lb * MD * 1024)
                          : (ws + OFF_C2P + (size_t)lb * MD * 1024);
    #pragma unroll
    for (int mi = 0; mi < 4; mi++) {
        #pragma unroll
        for (int ni = 0; ni < 4; ni++) {
            int gn = ntile * 256 + wave * 64 + ni * 16 + fr;
            #pragma unroll
            for (int rr = 0; rr < 4; rr++) {
                int co = mi * 16 + fq * 4 + rr;
                dst[(size_t)co * 1024 + gn] = acc[mi][ni][rr];
            }
        }
    }
}

// ---------------- reduce conv2 partial into X2 ----------------
__global__ __launch_bounds__(256) void kc2red(float* __restrict__ ws) {
    size_t i = ((size_t)blockIdx.x * 256 + threadIdx.x) * 8;
    float4 a0 = *(float4*)(ws + OFF_X2 + i);
    float4 a1 = *(float4*)(ws + OFF_X2 + i + 4);
    const float* p = ws + OFF_C2P + i;
    float4 b0 = *(const float4*)p;
    float4 b1 = *(const float4*)(p + 4);
    a0.x += b0.x; a0.y += b0.y; a0.z += b0.z; a0.w += b0.w;
    a1.x += b1.x; a1.y += b1.y; a1.z += b1.z; a1.w += b1.w;
    *(float4*)(ws + OFF_X2 + i) = a0;
    *(float4*)(ws + OFF_X2 + i + 4) = a1;
}

// ---------------- conv3 1x1 64->2 + bias ----------------
__global__ __launch_bounds__(256) void kconv3(const float* __restrict__ lw3,
                                              const float* __restrict__ lb3,
                                              float* __restrict__ ws) {
    __shared__ float w3s[2][64];
    int bid = blockIdx.x;
    int tile = bid & 15;
    int lb = bid >> 4;
    int l = lb >> 4;
    int t = threadIdx.x;
    if (t < 128) w3s[t >> 6][t & 63] = lw3[(size_t)(l * 2 + (t >> 6)) * MD + (t & 63)];
    __syncthreads();
    const float* t2p = ws + OFF_T2 + (size_t)lb * MD * 4096;
    int hw = tile * 256 + t;
    float a0 = lb3[l * 2], a1 = lb3[l * 2 + 1];
    for (int c2 = 0; c2 < MD; c2++) {
        float v = t2p[(size_t)c2 * 4096 + hw];
        a0 += v * w3s[0][c2];
        a1 += v * w3s[1][c2];
    }
    float* r3 = ws + OFF_RAW3 + (size_t)lb * 2 * 4096;
    r3[hw] = a0;
    r3[4096 + hw] = a1;
}

// ---------------- pool 4x4 + channel softmax -> patch outputs ----------------
__global__ __launch_bounds__(256) void kpool(const float* __restrict__ ws, float* __restrict__ out) {
    int lb = blockIdx.x;
    int t = threadIdx.x;
    int gy = t >> 4, gx = t & 15;
    const float* r3 = ws + OFF_RAW3 + (size_t)lb * 2 * 4096;
    float pl[2];
    #pragma unroll
    for (int ch = 0; ch < 2; ch++) {
        const float* basep = r3 + ch * 4096;
        float s = 0.f;
        #pragma unroll
        for (int dy = 0; dy < 4; dy++)
            #pragma unroll
            for (int dx = 0; dx < 4; dx++)
                s += basep[(gy * 4 + dy) * 64 + gx * 4 + dx];
        pl[ch] = s * (1.f / 16.f);
    }
    out[O_PLG + lb * NNQ + t] = pl[1] - pl[0];
    out[O_PSC + lb * NNQ + t] = 1.f / (1.f + expf(pl[0] - pl[1]));
}

// ---------------- bilinear resize 64x64 -> 240x240 (half-pixel, clamped) -------------
__global__ __launch_bounds__(256) void kresize(const float* __restrict__ ws, float* __restrict__ out) {
    int id = blockIdx.x * 256 + threadIdx.x;
    int ox = id % IMGSZ;
    int tmp = id / IMGSZ;
    int oy = tmp % IMGSZ;
    int tmp2 = tmp / IMGSZ;
    int ch = tmp2 & 1;
    int lb = tmp2 >> 1;
    const float S = 64.f / 240.f;
    float xs = fminf(fmaxf((ox + 0.5f) * S - 0.5f, 0.f), 63.f);
    float ys = fminf(fmaxf((oy + 0.5f) * S - 0.5f, 0.f), 63.f);
    int x0 = (int)xs, y0 = (int)ys;
    float fx = xs - x0, fy = ys - y0;
    int x1 = min(x0 + 1, 63), y1 = min(y0 + 1, 63);
    const float* basep = ws + OFF_RAW3 + (size_t)(lb * 2 + ch) * 4096;
    float v00 = basep[y0 * 64 + x0], v01 = basep[y0 * 64 + x1];
    float v10 = basep[y1 * 64 + x0], v11 = basep[y1 * 64 + x1];
    float v = (1.f - fy) * ((1.f - fx) * v00 + fx * v01) + fy * ((1.f - fx) * v10 + fx * v11);
    out[O_LOC + id] = v;
}

// ---------------- GAP/GMP pooled vector (many-block, coalesced) ----------------
__global__ __launch_bounds__(256) void kgap(float* __restrict__ ws,
                                            const float* __restrict__ pool_logits) {
    int bid = blockIdx.x;
    int dchunk = bid % 12;
    int lb = bid / 12;
    int l = lb >> 4;
    int t = threadIdx.x;
    int r = t >> 2, p = t & 3;
    int d = dchunk * 64 + r;
    const float* row = ws + OFF_CMAP + (size_t)lb * DD * NNQ + (size_t)d * NNQ + p * 64;
    float s = 0.f, mx = -1e30f, mn = 1e30f;
    #pragma unroll
    for (int i = 0; i < 16; i++) {
        float4 v = *(const float4*)(row + i * 4);
        s += v.x + v.y + v.z + v.w;
        mx = fmaxf(mx, fmaxf(fmaxf(v.x, v.y), fmaxf(v.z, v.w)));
        mn = fminf(mn, fminf(fminf(v.x, v.y), fminf(v.z, v.w)));
    }
    s += __shfl_xor(s, 1, 64); s += __shfl_xor(s, 2, 64);
    mx = fmaxf(mx, __shfl_xor(mx, 1, 64)); mx = fmaxf(mx, __shfl_xor(mx, 2, 64));
    mn = fminf(mn, __shfl_xor(mn, 1, 64)); mn = fminf(mn, __shfl_xor(mn, 2, 64));
    if (p == 0) {
        float p0 = pool_logits[l * 2], p1 = pool_logits[l * 2 + 1];
        float mxp = fmaxf(p0, p1);
        float e0 = expf(p0 - mxp), e1 = expf(p1 - mxp);
        float pw0 = e0 / (e0 + e1), pw1 = e1 / (e0 + e1);
        const float* bns = ws + OFF_BNSH + l * DD;
        const float* bnb = ws + OFF_BNSH + LLY * DD + l * DD;
        float scv = bns[d], bov = bnb[d];
        float gap = scv * (s * (1.f / NNQ)) + bov;
        float gmp = (scv >= 0.f) ? (scv * mx + bov) : (scv * mn + bov);
        ws[OFF_PGL + lb * DD + d] = pw0 * gap + pw1 * gmp;
    }
}

// ---------------- global head tail: MLP + LN from pooled ----------------
__global__ __launch_bounds__(256) void kglob2(const float* __restrict__ ws,
                                              const float* __restrict__ pool_logits,
                                              const float* __restrict__ mw1,
                                              const float* __restrict__ mlng,
                                              const float* __restrict__ mlnb,
                                              const float* __restrict__ mw2,
                                              const float* __restrict__ mb2,
                                              float* __restrict__ out) {
    __shared__ float pooled[DD];
    __shared__ float zbuf[HH];
    __shared__ float hbuf[HH];
    __shared__ float sm[4];
    int lb = blockIdx.x;
    int l = lb >> 4;
    int b = lb & 15;
    int t = threadIdx.x;
    float p0 = pool_logits[l * 2], p1 = pool_logits[l * 2 + 1];
    float mx = fmaxf(p0, p1);
    float e0 = expf(p0 - mx), e1 = expf(p1 - mx);
    float pw0 = e0 / (e0 + e1), pw1 = e1 / (e0 + e1);
    if (b == 0 && t < 2) out[O_PW + l * 2 + t] = (t == 0) ? pw0 : pw1;

    for (int d = t; d < DD; d += 256) pooled[d] = ws[OFF_PGL + lb * DD + d];
    __syncthreads();
    if (t < HH) {
        const float* wrow = mw1 + (size_t)(l * HH + t) * DD;
        float a = 0.f;
        for (int d2 = 0; d2 < DD; d2++) a += pooled[d2] * wrow[d2];
        zbuf[t] = a;
    }
    __syncthreads();
    float zv = (t < HH) ? zbuf[t] : 0.f;
    float s1r = blockReduceSum(zv, sm);
    float s2r = blockReduceSum(zv * zv, sm);
    float mean = s1r * (1.f / HH);
    float var = s2r * (1.f / HH) - mean * mean;
    float rstd = rsqrtf(var + 1e-5f);
    if (t < HH) {
        float h = (zbuf[t] - mean) * rstd * mlng[l * HH + t] + mlnb[l * HH + t];
        hbuf[t] = fmaxf(h, 0.f);
    }
    __syncthreads();
    float hv = (t < HH) ? hbuf[t] : 0.f;
    float w0v = (t < HH) ? mw2[(size_t)(l * 2 + 0) * HH + t] : 0.f;
    float w1v = (t < HH) ? mw2[(size_t)(l * 2 + 1) * HH + t] : 0.f;
    float s0 = blockReduceSum(hv * w0v, sm);
    float s1 = blockReduceSum(hv * w1v, sm);
    if (t == 0) out[O_GLG + lb] = (s1 + mb2[l * 2 + 1]) - (s0 + mb2[l * 2]);
}

extern "C" void kernel_launch(void* const* d_in, const int* in_sizes, int n_in,
                              void* d_out, int out_size, void* d_ws, size_t ws_size,
                              hipStream_t stream) {
    const float* query      = (const float*)d_in[0];
    const float* prompt     = (const float*)d_in[1];
    const float* sharebn_g  = (const float*)d_in[2];
    const float* sharebn_b  = (const float*)d_in[3];
    const float* lw1        = (const float*)d_in[4];
    const float* lbn1g      = (const float*)d_in[5];
    const float* lbn1b      = (const float*)d_in[6];
    const float* lwt1       = (const float*)d_in[7];
    const float* lbt1       = (const float*)d_in[8];
    const float* lw2        = (const float*)d_in[9];
    const float* lbn2g      = (const float*)d_in[10];
    const float* lbn2b      = (const float*)d_in[11];
    const float* lwt2       = (const float*)d_in[12];
    const float* lbt2       = (const float*)d_in[13];
    const float* lw3        = (const float*)d_in[14];
    const float* lb3        = (const float*)d_in[15];
    const float* pool_logits= (const float*)d_in[16];
    const float* mw1        = (const float*)d_in[17];
    const float* mlng       = (const float*)d_in[18];
    const float* mlnb       = (const float*)d_in[19];
    const float* mw2        = (const float*)d_in[20];
    const float* mb2        = (const float*)d_in[21];
    float* out = (float*)d_out;
    float* ws = (float*)d_ws;

    hipLaunchKernelGGL(knormq, dim3(LLY*BB*NNQ), dim3(192), 0, stream, query, ws);
    hipLaunchKernelGGL(ksimm, dim3(LBTOT*16), dim3(512), 0, stream, prompt, ws);
    hipLaunchKernelGGL(kpost, dim3(LBTOT*16), dim3(256), 0, stream, query, prompt, ws, out);
    hipLaunchKernelGGL(kbnstats, dim3(LLY*DD), dim3(256), 0, stream,
                       ws + OFF_CMAP, DD, NNQ, sharebn_g, sharebn_b, ws + OFF_BNSH);
    // conv1 via MFMA, split-K x6
    hipLaunchKernelGGL(kw1cvt, dim3(LLY*HH), dim3(256), 0, stream, lw1, ws);
    hipLaunchKernelGGL(kbn1cvt, dim3(LBTOT*48), dim3(256), 0, stream, ws);
    hipLaunchKernelGGL(kconv1m, dim3(LBTOT*12), dim3(256), 0, stream, ws);
    hipLaunchKernelGGL(kc1red, dim3(768), dim3(256), 0, stream, ws);
    hipLaunchKernelGGL(kbnstats, dim3(LLY*HH), dim3(256), 0, stream,
                       ws + OFF_X1, HH, 256, lbn1g, lbn1b, ws + OFF_BN1);
    // convT1 via MFMA: x1b = bf16(relu(bn1(X1))) [n][ci] in T2; wt1b in T2+WT1B_SH
    hipLaunchKernelGGL(kxcvt, dim3(LBTOT*8), dim3(256), 0, stream,
                       ws + OFF_X1, ws + OFF_BN1, (unsigned short*)(ws + OFF_T2) + X1B_SH,
                       HH, 256, 4, 2);
    hipLaunchKernelGGL(kwtcvt, dim3(LLY*HH), dim3(128), 0, stream,
                       lwt1, (unsigned short*)(ws + OFF_T2) + WT1B_SH, HH, HH);
    hipLaunchKernelGGL(kconvTm, dim3(LBTOT*4*2), dim3(256), 0, stream,
                       (const unsigned short*)(ws + OFF_T2) + X1B_SH,
                       (const unsigned short*)(ws + OFF_T2) + WT1B_SH,
                       lbt1, ws + OFF_T1, HH, HH, 4, 1, 2);
    // conv2 via MFMA, split-K x2
    hipLaunchKernelGGL(kt1cvt, dim3(LBTOT*32), dim3(256), 0, stream, ws);
    hipLaunchKernelGGL(kw2cvt, dim3(LLY*MD), dim3(256), 0, stream, lw2, ws);
    hipLaunchKernelGGL(kconv2m, dim3(LBTOT*8), dim3(256), 0, stream, ws);
    hipLaunchKernelGGL(kc2red, dim3(1536), dim3(256), 0, stream, ws);
    hipLaunchKernelGGL(kbnstats, dim3(LLY*MD), dim3(256), 0, stream,
                       ws + OFF_X2, MD, 1024, lbn2g, lbn2b, ws + OFF_BN2);
    // convT2 via MFMA: x2b = bf16(relu(bn2(X2))) [n][ci] in X1 region; wt2b in X2 region
    hipLaunchKernelGGL(kxcvt, dim3(LBTOT*16), dim3(256), 0, stream,
                       ws + OFF_X2, ws + OFF_BN2, (unsigned short*)(ws + OFF_X1),
                       MD, 1024, 16, 1);
    hipLaunchKernelGGL(kwtcvt, dim3(LLY*MD), dim3(128), 0, stream,
                       lwt2, (unsigned short*)(ws + OFF_X2), MD, MD);
    hipLaunchKernelGGL(kconvTm, dim3(LBTOT*4*4), dim3(256), 0, stream,
                       (const unsigned short*)(ws + OFF_X1),
                       (const unsigned short*)(ws + OFF_X2),
                       lbt2, ws + OFF_T2, MD, MD, 5, 4, 1);
    hipLaunchKernelGGL(kconv3, dim3(LBTOT*16), dim3(256), 0, stream, lw3, lb3, ws);
    hipLaunchKernelGGL(kpool, dim3(LBTOT), dim3(256), 0, stream, ws, out);
    hipLaunchKernelGGL(kresize, dim3(LLY*BB*2*IMGSZ*IMGSZ/256), dim3(256), 0, stream, ws, out);
    hipLaunchKernelGGL(kgap, dim3(LBTOT*12), dim3(256), 0, stream, ws, pool_logits);
    hipLaunchKernelGGL(kglob2, dim3(LBTOT), dim3(256), 0, stream,
                       ws, pool_logits, mw1, mlng, mlnb, mw2, mb2, out);
}

// Round 12
// 489.972 us; speedup vs baseline: 1.1608x; 1.0544x over previous
//
#include <hip/hip_runtime.h>
#include <hip/hip_bf16.h>
#include <math.h>

#define LLY 3
#define BB 16
#define NNQ 256
#define DD 768
#define MMP 2048
#define HH 128
#define MD 64
#define IMGSZ 240
#define LBTOT (LLY*BB)

// ---------------- workspace layout (floats) ----------------
#define OFF_INVQ 0
#define OFF_INVP (OFF_INVQ + LLY*BB*NNQ)
#define OFF_CMAP (OFF_INVP + LLY*BB*MMP)
#define OFF_BNSH (OFF_CMAP + LLY*BB*DD*NNQ)
#define OFF_X1   (OFF_BNSH + 2*LLY*DD)
#define OFF_BN1  (OFF_X1 + LLY*BB*HH*256)
#define OFF_T1   (OFF_BN1 + 2*LLY*HH)
#define OFF_X2   (OFF_T1 + LLY*BB*HH*1024)
#define OFF_BN2  (OFF_X2 + LLY*BB*MD*1024)
#define OFF_T2   (OFF_BN2 + 2*LLY*MD)
#define OFF_RAW3 (OFF_T2 + LLY*BB*MD*4096)
#define WS_FLOATS (OFF_RAW3 + LLY*BB*2*4096)
#define T1BSH (LBTOT*1024*HH)      // shorts
#define SQH   (LBTOT*NNQ*DD)       // shorts per q-split plane
#define OFF_C1P (OFF_T2 + 4718592)
#define OFF_C2P (OFF_T2 + 3256320)
#define OFF_PGL OFF_X1
// transient bf16 scratch (time-multiplexed):
//   x1b  (bf16 [lb][256][128])  T2 shorts [0, 1572864)
//   wt1b (bf16 [l][4][128][128])T2 shorts [1600000, 1796608)
//   t1B  overwrites x1b/wt1b after convT1m
//   x2b  (bf16 [lb][1024][64])  X1 region
//   wt2b (bf16 [l][4][64][64])  X2 region start
#define X1B_SH 0
#define WT1B_SH 1600000

// ---------------- output layout (floats) ----------------
#define O_RES 0
#define O_PSC (O_RES + LLY*BB*NNQ)
#define O_PLG (O_PSC + LLY*BB*NNQ)
#define O_GLG (O_PLG + LLY*BB*NNQ)
#define O_LOC (O_GLG + LLY*BB)
#define O_PW  (O_LOC + LLY*BB*2*IMGSZ*IMGSZ)
#define O_IDX (O_PW + LLY*2)
#define O_ALN (O_IDX + LLY*BB*NNQ)

typedef __attribute__((ext_vector_type(8))) short bf16x8;
typedef __attribute__((ext_vector_type(4))) float f32x4;

__device__ __forceinline__ unsigned short f2bf(float f) {
    __hip_bfloat16 h = __float2bfloat16(f);
    unsigned short u;
    __builtin_memcpy(&u, &h, sizeof(u));
    return u;
}
__device__ __forceinline__ float bf2f(unsigned short h) {
    return __uint_as_float(((unsigned int)h) << 16);
}

__device__ __forceinline__ float blockReduceSum(float v, float* sm) {
    for (int o = 32; o; o >>= 1) v += __shfl_down(v, o, 64);
    __syncthreads();
    if ((threadIdx.x & 63) == 0) sm[threadIdx.x >> 6] = v;
    __syncthreads();
    return sm[0] + sm[1] + sm[2] + sm[3];
}

// ------- fused: query row L2-norm + normalized bf16 hi/lo split (into T2 region) -----
__global__ __launch_bounds__(192) void knormq(const float* __restrict__ query,
                                              float* __restrict__ ws) {
    __shared__ float sm[3];
    int row = blockIdx.x;
    int t = threadIdx.x;
    float4 v = *(const float4*)(query + (size_t)row * DD + t * 4);
    float ss = v.x * v.x + v.y * v.y + v.z * v.z + v.w * v.w;
    for (int o = 32; o; o >>= 1) ss += __shfl_down(ss, o, 64);
    if ((t & 63) == 0) sm[t >> 6] = ss;
    __syncthreads();
    ss = sm[0] + sm[1] + sm[2];
    float iv = 1.0f / fmaxf(sqrtf(ss), 1e-12f);
    if (t == 0) ws[OFF_INVQ + row] = iv;
    unsigned short* qh = (unsigned short*)(ws + OFF_T2);
    unsigned short* ql = qh + SQH;
    float e[4] = {v.x * iv, v.y * iv, v.z * iv, v.w * iv};
    unsigned int hp[2], lp[2];
    #pragma unroll
    for (int j = 0; j < 2; j++) {
        unsigned short h0 = f2bf(e[2*j]), h1 = f2bf(e[2*j+1]);
        unsigned short l0 = f2bf(e[2*j] - bf2f(h0)), l1 = f2bf(e[2*j+1] - bf2f(h1));
        hp[j] = (unsigned int)h0 | ((unsigned int)h1 << 16);
        lp[j] = (unsigned int)l0 | ((unsigned int)l1 << 16);
    }
    *(uint2*)(qh + (size_t)row * DD + t * 4) = make_uint2(hp[0], hp[1]);
    *(uint2*)(ql + (size_t)row * DD + t * 4) = make_uint2(lp[0], lp[1]);
}

// ---- sim GEMM: 128p x 256q block, 8 waves of 64x64, fused p-norm, 40-short stride ---
__global__ __launch_bounds__(512) void ksimm(const float* __restrict__ prompt, float* __restrict__ ws) {
    __shared__ __align__(16) unsigned short Ah[128][40];
    __shared__ __align__(16) unsigned short Al[128][40];
    __shared__ __align__(16) unsigned short Bh[256][40];
    __shared__ __align__(16) unsigned short Bl[256][40];
    __shared__ float invL[128];
    int bid = blockIdx.x;
    int mt = bid & 15;
    int lb = bid >> 4;
    int t = threadIdx.x;
    int lane = t & 63, wave = t >> 6;
    int wm = wave >> 2, wn = wave & 3;
    int fr = lane & 15, fq = lane >> 4;
    const unsigned short* qh = (const unsigned short*)(ws + OFF_T2);
    const unsigned short* ql = qh + SQH;
    const float* pbase = prompt + (size_t)lb * MMP * DD + (size_t)(mt * 128) * DD;

    float ssq[2] = {0.f, 0.f};

    f32x4 acc[4][4];
    #pragma unroll
    for (int mi = 0; mi < 4; mi++)
        #pragma unroll
        for (int ni = 0; ni < 4; ni++) acc[mi][ni] = (f32x4){0.f, 0.f, 0.f, 0.f};

    for (int kc = 0; kc < DD; kc += 32) {
        __syncthreads();
        #pragma unroll
        for (int i = 0; i < 2; i++) {
            int f = t + i * 512;
            int row = f >> 3, c4 = f & 7;
            float4 v = *(const float4*)(pbase + (size_t)row * DD + kc + c4 * 4);
            ssq[i] += v.x * v.x + v.y * v.y + v.z * v.z + v.w * v.w;
            unsigned short h0 = f2bf(v.x), h1 = f2bf(v.y), h2 = f2bf(v.z), h3 = f2bf(v.w);
            unsigned short l0 = f2bf(v.x - bf2f(h0)), l1 = f2bf(v.y - bf2f(h1));
            unsigned short l2 = f2bf(v.z - bf2f(h2)), l3 = f2bf(v.w - bf2f(h3));
            uint2 hp = make_uint2((unsigned int)h0 | ((unsigned int)h1 << 16),
                                  (unsigned int)h2 | ((unsigned int)h3 << 16));
            uint2 lp = make_uint2((unsigned int)l0 | ((unsigned int)l1 << 16),
                                  (unsigned int)l2 | ((unsigned int)l3 << 16));
            *(uint2*)&Ah[row][c4 * 4] = hp;
            *(uint2*)&Al[row][c4 * 4] = lp;
        }
        #pragma unroll
        for (int i = 0; i < 2; i++) {
            int f = t + i * 512;
            int row = f >> 2, sg = f & 3;
            size_t go = (size_t)(lb * NNQ + row) * DD + kc + sg * 8;
            *(uint4*)&Bh[row][sg * 8] = *(const uint4*)(qh + go);
            *(uint4*)&Bl[row][sg * 8] = *(const uint4*)(ql + go);
        }
        __syncthreads();
        bf16x8 ah[4], al4[4], bh[4], bl4[4];
        #pragma unroll
        for (int mi = 0; mi < 4; mi++) {
            ah[mi]  = *(const bf16x8*)&Ah[wm * 64 + mi * 16 + fr][fq * 8];
            al4[mi] = *(const bf16x8*)&Al[wm * 64 + mi * 16 + fr][fq * 8];
        }
        #pragma unroll
        for (int ni = 0; ni < 4; ni++) {
            bh[ni]  = *(const bf16x8*)&Bh[wn * 64 + ni * 16 + fr][fq * 8];
            bl4[ni] = *(const bf16x8*)&Bl[wn * 64 + ni * 16 + fr][fq * 8];
        }
        #pragma unroll
        for (int mi = 0; mi < 4; mi++)
            #pragma unroll
            for (int ni = 0; ni < 4; ni++) {
                acc[mi][ni] = __builtin_amdgcn_mfma_f32_16x16x32_bf16(ah[mi],  bh[ni],  acc[mi][ni], 0, 0, 0);
                acc[mi][ni] = __builtin_amdgcn_mfma_f32_16x16x32_bf16(ah[mi],  bl4[ni], acc[mi][ni], 0, 0, 0);
                acc[mi][ni] = __builtin_amdgcn_mfma_f32_16x16x32_bf16(al4[mi], bh[ni],  acc[mi][ni], 0, 0, 0);
            }
    }
    #pragma unroll
    for (int i = 0; i < 2; i++) {
        float s = ssq[i];
        s += __shfl_xor(s, 1, 64);
        s += __shfl_xor(s, 2, 64);
        s += __shfl_xor(s, 4, 64);
        if ((t & 7) == 0) {
            int row = (t >> 3) + 64 * i;
            float iv = 1.0f / fmaxf(sqrtf(s), 1e-12f);
            invL[row] = iv;
            ws[OFF_INVP + lb * MMP + mt * 128 + row] = iv;
        }
    }
    __syncthreads();
    float* bestv = ws + OFF_X1;
    float* besti = ws + OFF_X1 + (size_t)LBTOT * NNQ * 32;
    #pragma unroll
    for (int ni = 0; ni < 4; ni++) {
        float bv = -1e30f; int bi = 0;
        #pragma unroll
        for (int mi = 0; mi < 4; mi++)
            #pragma unroll
            for (int rr = 0; rr < 4; rr++) {
                int lm = wm * 64 + mi * 16 + fq * 4 + rr;
                float s = acc[mi][ni][rr] * invL[lm];
                int m = mt * 128 + lm;
                if (s > bv) { bv = s; bi = m; }
            }
        #pragma unroll
        for (int o = 16; o <= 32; o <<= 1) {
            float ov = __shfl_xor(bv, o, 64);
            int oi = __shfl_xor(bi, o, 64);
            if (ov > bv || (ov == bv && oi < bi)) { bv = ov; bi = oi; }
        }
        if (fq == 0) {
            int q = wn * 64 + ni * 16 + fr;
            size_t slot = (size_t)(lb * NNQ + q) * 32 + wm * 16 + mt;
            bestv[slot] = bv;
            besti[slot] = (float)bi;
        }
    }
}

// --- argmax finalize + residual/idx/aligned/ctx; cmap written via LDS transpose ------
__global__ __launch_bounds__(256) void kpost(const float* __restrict__ query,
                                             const float* __restrict__ prompt,
                                             float* __restrict__ ws,
                                             float* __restrict__ out) {
    __shared__ float red_v[16];
    __shared__ int   red_i[16];
    __shared__ float Lctx[DD * 17];
    int bid = blockIdx.x;
    int nt = bid & 15;
    int lb = bid >> 4;
    int t = threadIdx.x;
    const float* bestv = ws + OFF_X1;
    const float* besti = ws + OFF_X1 + (size_t)LBTOT * NNQ * 32;
    if (t < 16) {
        int q = nt * 16 + t;
        const float* bv = bestv + (size_t)(lb * NNQ + q) * 32;
        const float* bi = besti + (size_t)(lb * NNQ + q) * 32;
        float best = -1e30f; int bidx2 = 0;
        for (int mtt = 0; mtt < 16; mtt++)
            #pragma unroll
            for (int wm = 0; wm < 2; wm++) {
                float v = bv[wm * 16 + mtt];
                if (v > best) { best = v; bidx2 = (int)bi[wm * 16 + mtt]; }
            }
        red_v[t] = best; red_i[t] = bidx2;
        out[O_RES + lb * NNQ + q] = 0.5f * (1.0f - best);
        out[O_IDX + lb * NNQ + q] = (float)bidx2;
    }
    __syncthreads();
    const float* qbase = query + (size_t)(lb * NNQ + nt * 16) * DD;
    const float* pbase = prompt + (size_t)lb * MMP * DD;
    const float* invq = ws + OFF_INVQ + lb * NNQ + nt * 16;
    const float* invp = ws + OFF_INVP + lb * MMP;
    int c = t & 15;
    int nn = t >> 4;
    int gn = nt * 16 + nn;
    int midx = red_i[nn];
    float ip = invp[midx];
    float iq = invq[nn];
    const float* prow = pbase + (size_t)midx * DD;
    const float* qrow = qbase + (size_t)nn * DD;
    float* aln = out + O_ALN + (size_t)(lb * NNQ + gn) * DD;
    for (int jj = 0; jj < DD / 16; jj++) {
        int d = c + jj * 16;
        float pvr = prow[d];
        float qv = qrow[d] * iq;
        float av = pvr * ip;
        float cx = qv + fabsf(qv - av);
        aln[d] = pvr;
        Lctx[d * 17 + nn] = cx;
    }
    __syncthreads();
    float* cm = ws + OFF_CMAP + (size_t)lb * DD * NNQ + nt * 16;
    int nl = t & 15, dd = t >> 4;
    for (int jj = 0; jj < DD / 16; jj++) {
        int d = jj * 16 + dd;
        cm[(size_t)d * NNQ + nl] = Lctx[d * 17 + nl];
    }
}

// ---------------- BN batch stats (per l,c over B x SP), biased var ----------------
__global__ __launch_bounds__(256) void kbnstats(const float* __restrict__ x, int C, int SP,
                                                const float* __restrict__ g,
                                                const float* __restrict__ b,
                                                float* __restrict__ outSB) {
    __shared__ float sm[4];
    int bid = blockIdx.x;
    int c = bid % C;
    int l = bid / C;
    int t = threadIdx.x;
    float s = 0.f, sq = 0.f;
    for (int bb2 = 0; bb2 < BB; ++bb2) {
        const float* p = x + ((size_t)(l * BB + bb2) * C + c) * SP;
        for (int i = t; i < SP; i += 256) { float v = p[i]; s += v; sq += v * v; }
    }
    s = blockReduceSum(s, sm);
    sq = blockReduceSum(sq, sm);
    if (t == 0) {
        float inv = 1.0f / (float)(BB * SP);
        float m = s * inv;
        float var = sq * inv - m * m;
        float sc = g[l * C + c] * rsqrtf(var + 1e-5f);
        float bo = b[l * C + c] - m * sc;
        outSB[l * C + c] = sc;
        outSB[LLY * C + l * C + c] = bo;
    }
}

// ---------------- weight repack: lw1 f32 [l][co][ci][9] -> bf16 [l][tap][co][ci] -----
__global__ __launch_bounds__(256) void kw1cvt(const float* __restrict__ lw1, float* __restrict__ ws) {
    unsigned short* w1B = (unsigned short*)(ws + OFF_X2);
    int bid = blockIdx.x;
    int l = bid / HH, co = bid % HH;
    int t = threadIdx.x;
    for (int c0 = 0; c0 < DD; c0 += 256) {
        int ci = c0 + t;
        const float* src = lw1 + ((size_t)(l * HH + co) * DD + ci) * 9;
        #pragma unroll
        for (int tap = 0; tap < 9; tap++) {
            w1B[((size_t)((l * 9 + tap) * HH + co)) * DD + ci] = f2bf(src[tap]);
        }
    }
}

// ---------------- BN-fold + transpose: cmap f32 [lb][ci][n] -> bf16 cmT [lb][n][ci] --
__global__ __launch_bounds__(256) void kbn1cvt(float* __restrict__ ws) {
    __shared__ float Ld[64][65];
    unsigned short* cmT = (unsigned short*)(ws + OFF_T2);
    int bid = blockIdx.x;
    int nt = bid & 3;
    int r = bid >> 2;
    int ct = r % 12;
    int lb = r / 12;
    int l = lb >> 4;
    int t = threadIdx.x;
    const float* cmap = ws + OFF_CMAP + (size_t)lb * DD * NNQ;
    const float* bns = ws + OFF_BNSH + l * DD;
    const float* bnb = ws + OFF_BNSH + LLY * DD + l * DD;
    #pragma unroll
    for (int i = 0; i < 4; i++) {
        int f = t + i * 256;
        int row = f >> 4, c4 = f & 15;
        int ci = ct * 64 + row;
        float4 v = *(const float4*)(cmap + (size_t)ci * NNQ + nt * 64 + c4 * 4);
        float s = bns[ci], bo = bnb[ci];
        Ld[row][c4*4+0] = v.x * s + bo; Ld[row][c4*4+1] = v.y * s + bo;
        Ld[row][c4*4+2] = v.z * s + bo; Ld[row][c4*4+3] = v.w * s + bo;
    }
    __syncthreads();
    #pragma unroll
    for (int i = 0; i < 2; i++) {
        int f = t + i * 256;
        int row = f >> 3, seg = f & 7;
        unsigned int pk[4];
        #pragma unroll
        for (int e = 0; e < 4; e++) {
            unsigned int lo = f2bf(Ld[seg * 8 + 2 * e][row]);
            unsigned int hi = f2bf(Ld[seg * 8 + 2 * e + 1][row]);
            pk[e] = lo | (hi << 16);
        }
        uint4 o = make_uint4(pk[0], pk[1], pk[2], pk[3]);
        *(uint4*)(cmT + ((size_t)(lb * NNQ + nt * 64 + row)) * DD + ct * 64 + seg * 8) = o;
    }
}

// ------- conv1 MFMA, split-K x6: 128co x 128n per block, 18 of 108 kc-chunks each ----
__global__ __launch_bounds__(256) void kconv1m(float* __restrict__ ws) {
    __shared__ __align__(16) unsigned short Ab[128][72];
    __shared__ __align__(16) unsigned short Bb[128][72];
    int bid = blockIdx.x;
    int s = bid % 6;
    int ntile = (bid / 6) & 1;
    int lb = bid / 12;
    int l = lb >> 4;
    int t = threadIdx.x;
    int lane = t & 63;
    int wave = t >> 6;
    int wr = wave >> 1, wc = wave & 1;
    int fr = lane & 15, fq = lane >> 4;
    const unsigned short* w1B = (const unsigned short*)(ws + OFF_X2);
    const unsigned short* cmT = (const unsigned short*)(ws + OFF_T2);

    f32x4 acc[4][4];
    #pragma unroll
    for (int mi = 0; mi < 4; mi++)
        #pragma unroll
        for (int ni = 0; ni < 4; ni++) acc[mi][ni] = (f32x4){0.f, 0.f, 0.f, 0.f};

    for (int g = s * 18; g < s * 18 + 18; ++g) {
        int tap = g / 12;
        int kc = (g % 12) * 64;
        int dy = tap / 3 - 1, dx = tap % 3 - 1;
        const unsigned short* wpl = w1B + (size_t)((l * 9 + tap) * HH) * DD;
        __syncthreads();
        #pragma unroll
        for (int i = 0; i < 4; i++) {
            int f = t + i * 256;
            int row = f >> 3, seg = f & 7;
            uint4 v = *(const uint4*)(wpl + (size_t)row * DD + kc + seg * 8);
            *(uint4*)&Ab[row][seg * 8] = v;
        }
        #pragma unroll
        for (int i = 0; i < 4; i++) {
            int f = t + i * 256;
            int row = f >> 3, seg = f & 7;
            int n = ntile * 128 + row;
            int y = (n >> 4) + dy, x = (n & 15) + dx;
            bool ok = ((unsigned)y < 16u) && ((unsigned)x < 16u);
            uint4 v = make_uint4(0u, 0u, 0u, 0u);
            if (ok) v = *(const uint4*)(cmT + ((size_t)(lb * NNQ + y * 16 + x)) * DD + kc + seg * 8);
            *(uint4*)&Bb[row][seg * 8] = v;
        }
        __syncthreads();
        #pragma unroll
        for (int kk = 0; kk < 64; kk += 32) {
            bf16x8 af[4], bfv[4];
            #pragma unroll
            for (int mi = 0; mi < 4; mi++)
                af[mi] = *(const bf16x8*)&Ab[wr * 64 + mi * 16 + fr][kk + fq * 8];
            #pragma unroll
            for (int ni = 0; ni < 4; ni++)
                bfv[ni] = *(const bf16x8*)&Bb[wc * 64 + ni * 16 + fr][kk + fq * 8];
            #pragma unroll
            for (int mi = 0; mi < 4; mi++)
                #pragma unroll
                for (int ni = 0; ni < 4; ni++)
                    acc[mi][ni] = __builtin_amdgcn_mfma_f32_16x16x32_bf16(af[mi], bfv[ni], acc[mi][ni], 0, 0, 0);
        }
    }
    float* dst = (s == 5) ? (ws + OFF_X1 + (size_t)lb * HH * 256)
                          : (ws + OFF_C1P + (size_t)(s * LBTOT + lb) * (HH * 256));
    #pragma unroll
    for (int mi = 0; mi < 4; mi++) {
        #pragma unroll
        for (int ni = 0; ni < 4; ni++) {
            int gn = ntile * 128 + wc * 64 + ni * 16 + fr;
            #pragma unroll
            for (int rr = 0; rr < 4; rr++) {
                int co = wr * 64 + mi * 16 + fq * 4 + rr;
                dst[(size_t)co * 256 + gn] = acc[mi][ni][rr];
            }
        }
    }
}

// ---------------- reduce conv1 partials into X1 ----------------
__global__ __launch_bounds__(256) void kc1red(float* __restrict__ ws) {
    size_t i = ((size_t)blockIdx.x * 256 + threadIdx.x) * 8;
    float4 a0 = *(float4*)(ws + OFF_X1 + i);
    float4 a1 = *(float4*)(ws + OFF_X1 + i + 4);
    #pragma unroll
    for (int s = 0; s < 5; s++) {
        const float* p = ws + OFF_C1P + (size_t)s * (LBTOT * HH * 256) + i;
        float4 b0 = *(const float4*)p;
        float4 b1 = *(const float4*)(p + 4);
        a0.x += b0.x; a0.y += b0.y; a0.z += b0.z; a0.w += b0.w;
        a1.x += b1.x; a1.y += b1.y; a1.z += b1.z; a1.w += b1.w;
    }
    *(float4*)(ws + OFF_X1 + i) = a0;
    *(float4*)(ws + OFF_X1 + i + 4) = a1;
}

// ---- generic: x f32 [lb][CI][SPIN] --BN+ReLU--> xb bf16 [lb][SPIN][CI] (transpose) --
__global__ __launch_bounds__(256) void kxcvt(const float* __restrict__ x,
                                             const float* __restrict__ sbsb,
                                             unsigned short* __restrict__ xb,
                                             int CI, int SPIN, int nT, int cT) {
    __shared__ float Ld[64][65];
    int bid = blockIdx.x;
    int nt = bid % nT;
    int r = bid / nT;
    int ct = r % cT;
    int lb = r / cT;
    int l = lb >> 4;
    int t = threadIdx.x;
    const float* sc = sbsb + l * CI;
    const float* bo = sbsb + LLY * CI + l * CI;
    #pragma unroll
    for (int i = 0; i < 4; i++) {
        int f = t + i * 256;
        int row = f >> 4, c4 = f & 15;
        int ci = ct * 64 + row;
        float4 v = *(const float4*)(x + ((size_t)lb * CI + ci) * SPIN + nt * 64 + c4 * 4);
        float s = sc[ci], b_ = bo[ci];
        Ld[row][c4*4+0] = fmaxf(v.x * s + b_, 0.f);
        Ld[row][c4*4+1] = fmaxf(v.y * s + b_, 0.f);
        Ld[row][c4*4+2] = fmaxf(v.z * s + b_, 0.f);
        Ld[row][c4*4+3] = fmaxf(v.w * s + b_, 0.f);
    }
    __syncthreads();
    int segs = CI >> 3;
    for (int f = t; f < 64 * segs; f += 256) {
        int row = f / segs, seg = f % segs;
        int sl = seg - ct * 8;
        if (sl < 0 || sl >= 8) continue;
        unsigned int pk[4];
        #pragma unroll
        for (int e = 0; e < 4; e++) {
            unsigned int lo = f2bf(Ld[sl * 8 + 2 * e][row]);
            unsigned int hi = f2bf(Ld[sl * 8 + 2 * e + 1][row]);
            pk[e] = lo | (hi << 16);
        }
        uint4 o = make_uint4(pk[0], pk[1], pk[2], pk[3]);
        *(uint4*)(xb + ((size_t)lb * SPIN + nt * 64 + row) * CI + ct * 64 + sl * 8) = o;
    }
}

// ---- convT weight repack: lwt f32 [l][ci][co][2][2] -> bf16 [l][pq][co][ci] ---------
__global__ __launch_bounds__(128) void kwtcvt(const float* __restrict__ lwt,
                                              unsigned short* __restrict__ dst,
                                              int CI, int CO) {
    int bid = blockIdx.x;
    int l = bid / CO, co = bid % CO;
    int t = threadIdx.x;
    if (t < CI) {
        const float* src = lwt + (((size_t)(l * CI + t) * CO + co) * 4);
        #pragma unroll
        for (int pq = 0; pq < 4; pq++) {
            dst[((size_t)((l * 4 + pq) * CO + co)) * CI + t] = f2bf(src[pq]);
        }
    }
}

// ---- convT1 as 4 per-pq MFMA GEMMs: 64co x 256n block, K=CI, upsample-scatter out ---
__global__ __launch_bounds__(256) void kconvTm(const unsigned short* __restrict__ xb,
                                               const unsigned short* __restrict__ wtb,
                                               const float* __restrict__ bt,
                                               float* __restrict__ xout,
                                               int CI, int CO, int gsh, int nTiles, int coTiles) {
    __shared__ __align__(16) unsigned short Ab[64][72];
    __shared__ __align__(16) unsigned short Bb[256][72];
    int bid = blockIdx.x;
    int ntile = bid % nTiles;
    int r = bid / nTiles;
    int cot = r % coTiles; r /= coTiles;
    int pq = r & 3;
    int lb = r >> 2;
    int l = lb >> 4;
    int SPIN = 1 << (2 * gsh);
    int t = threadIdx.x, lane = t & 63, wave = t >> 6;
    int fr = lane & 15, fq = lane >> 4;

    f32x4 acc[4][4];
    #pragma unroll
    for (int mi = 0; mi < 4; mi++)
        #pragma unroll
        for (int ni = 0; ni < 4; ni++) acc[mi][ni] = (f32x4){0.f, 0.f, 0.f, 0.f};

    for (int kc = 0; kc < CI; kc += 64) {
        __syncthreads();
        #pragma unroll
        for (int i = 0; i < 2; i++) {
            int f = t + i * 256;
            int row = f >> 3, seg = f & 7;
            *(uint4*)&Ab[row][seg * 8] =
                *(const uint4*)(wtb + ((size_t)((l * 4 + pq) * CO + cot * 64 + row)) * CI + kc + seg * 8);
        }
        #pragma unroll
        for (int i = 0; i < 8; i++) {
            int f = t + i * 256;
            int row = f >> 3, seg = f & 7;
            *(uint4*)&Bb[row][seg * 8] =
                *(const uint4*)(xb + ((size_t)lb * SPIN + ntile * 256 + row) * CI + kc + seg * 8);
        }
        __syncthreads();
        #pragma unroll
        for (int kk = 0; kk < 64; kk += 32) {
            bf16x8 af[4], bfv[4];
            #pragma unroll
            for (int mi = 0; mi < 4; mi++)
                af[mi] = *(const bf16x8*)&Ab[mi * 16 + fr][kk + fq * 8];
            #pragma unroll
            for (int ni = 0; ni < 4; ni++)
                bfv[ni] = *(const bf16x8*)&Bb[wave * 64 + ni * 16 + fr][kk + fq * 8];
            #pragma unroll
            for (int mi = 0; mi < 4; mi++)
                #pragma unroll
                for (int ni = 0; ni < 4; ni++)
                    acc[mi][ni] = __builtin_amdgcn_mfma_f32_16x16x32_bf16(af[mi], bfv[ni], acc[mi][ni], 0, 0, 0);
        }
    }
    int p = pq >> 1, q = pq & 1;
    int GIN = 1 << gsh;
    #pragma unroll
    for (int mi = 0; mi < 4; mi++) {
        #pragma unroll
        for (int rr = 0; rr < 4; rr++) {
            int co = cot * 64 + mi * 16 + fq * 4 + rr;
            float bias = bt[l * CO + co];
            float* orow = xout + ((size_t)(lb * CO + co)) * (4 * SPIN);
            #pragma unroll
            for (int ni = 0; ni < 4; ni++) {
                int n = ntile * 256 + wave * 64 + ni * 16 + fr;
                int h = n >> gsh, w = n & (GIN - 1);
                orow[(2 * h + p) * (2 * GIN) + 2 * w + q] = acc[mi][ni][rr] + bias;
            }
        }
    }
}

// ---- convT2 + fused conv3 (1x1 64->2): 64co x 256n, K=64; writes only RAW3 ----------
__global__ __launch_bounds__(256) void kconvT2f(const unsigned short* __restrict__ xb,
                                                const unsigned short* __restrict__ wtb,
                                                const float* __restrict__ bt,
                                                const float* __restrict__ lw3,
                                                const float* __restrict__ lb3,
                                                float* __restrict__ ws) {
    __shared__ __align__(16) unsigned short Ab[64][72];
    __shared__ __align__(16) unsigned short Bb[256][72];
    __shared__ float w3s[2][64];
    int bid = blockIdx.x;
    int ntile = bid & 3;
    int r = bid >> 2;
    int pq = r & 3;
    int lb = r >> 2;
    int l = lb >> 4;
    const int CI = MD, CO = MD, gsh = 5;
    int SPIN = 1 << (2 * gsh);
    int t = threadIdx.x, lane = t & 63, wave = t >> 6;
    int fr = lane & 15, fq = lane >> 4;
    if (t < 128) w3s[t >> 6][t & 63] = lw3[(size_t)(l * 2 + (t >> 6)) * MD + (t & 63)];

    f32x4 acc[4][4];
    #pragma unroll
    for (int mi = 0; mi < 4; mi++)
        #pragma unroll
        for (int ni = 0; ni < 4; ni++) acc[mi][ni] = (f32x4){0.f, 0.f, 0.f, 0.f};

    __syncthreads();
    #pragma unroll
    for (int i = 0; i < 2; i++) {
        int f = t + i * 256;
        int row = f >> 3, seg = f & 7;
        *(uint4*)&Ab[row][seg * 8] =
            *(const uint4*)(wtb + ((size_t)((l * 4 + pq) * CO + row)) * CI + seg * 8);
    }
    #pragma unroll
    for (int i = 0; i < 8; i++) {
        int f = t + i * 256;
        int row = f >> 3, seg = f & 7;
        *(uint4*)&Bb[row][seg * 8] =
            *(const uint4*)(xb + ((size_t)lb * SPIN + ntile * 256 + row) * CI + seg * 8);
    }
    __syncthreads();
    #pragma unroll
    for (int kk = 0; kk < 64; kk += 32) {
        bf16x8 af[4], bfv[4];
        #pragma unroll
        for (int mi = 0; mi < 4; mi++)
            af[mi] = *(const bf16x8*)&Ab[mi * 16 + fr][kk + fq * 8];
        #pragma unroll
        for (int ni = 0; ni < 4; ni++)
            bfv[ni] = *(const bf16x8*)&Bb[wave * 64 + ni * 16 + fr][kk + fq * 8];
        #pragma unroll
        for (int mi = 0; mi < 4; mi++)
            #pragma unroll
            for (int ni = 0; ni < 4; ni++)
                acc[mi][ni] = __builtin_amdgcn_mfma_f32_16x16x32_bf16(af[mi], bfv[ni], acc[mi][ni], 0, 0, 0);
    }
    // fused conv3: per-thread partial over (mi,rr) co's, reduce over fq lanes
    float s0[4] = {0.f, 0.f, 0.f, 0.f};
    float s1[4] = {0.f, 0.f, 0.f, 0.f};
    #pragma unroll
    for (int mi = 0; mi < 4; mi++) {
        #pragma unroll
        for (int rr = 0; rr < 4; rr++) {
            int co = mi * 16 + fq * 4 + rr;
            float bias = bt[l * CO + co];
            float w0 = w3s[0][co], w1 = w3s[1][co];
            #pragma unroll
            for (int ni = 0; ni < 4; ni++) {
                float val = acc[mi][ni][rr] + bias;
                s0[ni] += w0 * val;
                s1[ni] += w1 * val;
            }
        }
    }
    #pragma unroll
    for (int ni = 0; ni < 4; ni++) {
        s0[ni] += __shfl_xor(s0[ni], 16, 64); s0[ni] += __shfl_xor(s0[ni], 32, 64);
        s1[ni] += __shfl_xor(s1[ni], 16, 64); s1[ni] += __shfl_xor(s1[ni], 32, 64);
    }
    if (fq == 0) {
        int p = pq >> 1, q = pq & 1;
        float* r3 = ws + OFF_RAW3 + (size_t)lb * 2 * 4096;
        float b30 = lb3[l * 2], b31 = lb3[l * 2 + 1];
        #pragma unroll
        for (int ni = 0; ni < 4; ni++) {
            int n = ntile * 256 + wave * 64 + ni * 16 + fr;
            int h = n >> 5, w = n & 31;
            int opix = (2 * h + p) * 64 + 2 * w + q;
            r3[opix] = s0[ni] + b30;
            r3[4096 + opix] = s1[ni] + b31;
        }
    }
}

// ---------------- T1 f32 [lb][ci=128][n=1024] -> bf16 t1B [lb][n][ci] ----------------
__global__ __launch_bounds__(256) void kt1cvt(float* __restrict__ ws) {
    __shared__ float Ld[64][65];
    unsigned short* t1B = (unsigned short*)(ws + OFF_T2);
    int bid = blockIdx.x;
    int ntile = bid & 15;
    int r = bid >> 4;
    int ct = r & 1;
    int lb = r >> 1;
    int t = threadIdx.x;
    const float* t1p = ws + OFF_T1 + (size_t)lb * HH * 1024;
    #pragma unroll
    for (int i = 0; i < 4; i++) {
        int f = t + i * 256;
        int row = f >> 4, c4 = f & 15;
        float4 v = *(const float4*)(t1p + (size_t)(ct * 64 + row) * 1024 + ntile * 64 + c4 * 4);
        *(float4*)&Ld[row][c4 * 4] = v;
    }
    __syncthreads();
    #pragma unroll
    for (int i = 0; i < 2; i++) {
        int f = t + i * 256;
        int row = f >> 3, seg = f & 7;
        unsigned int pk[4];
        #pragma unroll
        for (int e = 0; e < 4; e++) {
            unsigned int lo = f2bf(Ld[seg * 8 + 2 * e][row]);
            unsigned int hi = f2bf(Ld[seg * 8 + 2 * e + 1][row]);
            pk[e] = lo | (hi << 16);
        }
        uint4 o = make_uint4(pk[0], pk[1], pk[2], pk[3]);
        *(uint4*)(t1B + ((size_t)(lb * 1024 + ntile * 64 + row)) * HH + ct * 64 + seg * 8) = o;
    }
}

// ---------------- weight repack: lw2 f32 [l][co][ci][9] -> bf16 [l][tap][co][ci] -----
__global__ __launch_bounds__(256) void kw2cvt(const float* __restrict__ lw2, float* __restrict__ ws) {
    unsigned short* w2B = (unsigned short*)(ws + OFF_T2) + T1BSH;
    int bid = blockIdx.x;
    int l = bid / MD, co = bid % MD;
    int t = threadIdx.x;
    if (t < HH) {
        int ci = t;
        const float* src = lw2 + ((size_t)(l * MD + co) * HH + ci) * 9;
        #pragma unroll
        for (int tap = 0; tap < 9; tap++) {
            w2B[((size_t)((l * 9 + tap) * MD + co)) * HH + ci] = f2bf(src[tap]);
        }
    }
}

// ------- conv2 MFMA, split-K x2: 64co x 256n per block, 9 of 18 kc-chunks each -------
__global__ __launch_bounds__(256) void kconv2m(float* __restrict__ ws) {
    __shared__ __align__(16) unsigned short Ab[64][72];
    __shared__ __align__(16) unsigned short Bb[256][72];
    int bid = blockIdx.x;
    int s = bid & 1;
    int ntile = (bid >> 1) & 3;
    int lb = bid >> 3;
    int l = lb >> 4;
    int t = threadIdx.x;
    int lane = t & 63;
    int wave = t >> 6;
    int fr = lane & 15, fq = lane >> 4;
    const unsigned short* t1B = (const unsigned short*)(ws + OFF_T2);
    const unsigned short* w2B = (const unsigned short*)(ws + OFF_T2) + T1BSH;

    f32x4 acc[4][4];
    #pragma unroll
    for (int mi = 0; mi < 4; mi++)
        #pragma unroll
        for (int ni = 0; ni < 4; ni++) acc[mi][ni] = (f32x4){0.f, 0.f, 0.f, 0.f};

    for (int g = s * 9; g < s * 9 + 9; ++g) {
        int tap = g >> 1;
        int kc = (g & 1) * 64;
        int dy = tap / 3 - 1, dx = tap % 3 - 1;
        const unsigned short* wpl = w2B + (size_t)((l * 9 + tap) * MD) * HH;
        __syncthreads();
        #pragma unroll
        for (int i = 0; i < 2; i++) {
            int f = t + i * 256;
            int row = f >> 3, seg = f & 7;
            uint4 v = *(const uint4*)(wpl + (size_t)row * HH + kc + seg * 8);
            *(uint4*)&Ab[row][seg * 8] = v;
        }
        #pragma unroll
        for (int i = 0; i < 8; i++) {
            int f = t + i * 256;
            int row = f >> 3, seg = f & 7;
            int n = ntile * 256 + row;
            int y = (n >> 5) + dy, x = (n & 31) + dx;
            bool ok = ((unsigned)y < 32u) && ((unsigned)x < 32u);
            uint4 v = make_uint4(0u, 0u, 0u, 0u);
            if (ok) v = *(const uint4*)(t1B + ((size_t)(lb * 1024 + y * 32 + x)) * HH + kc + seg * 8);
            *(uint4*)&Bb[row][seg * 8] = v;
        }
        __syncthreads();
        #pragma unroll
        for (int kk = 0; kk < 64; kk += 32) {
            bf16x8 af[4], bfv[4];
            #pragma unroll
            for (int mi = 0; mi < 4; mi++)
                af[mi] = *(const bf16x8*)&Ab[mi * 16 + fr][kk + fq * 8];
            #pragma unroll
            for (int ni = 0; ni < 4; ni++)
                bfv[ni] = *(const bf16x8*)&Bb[wave * 64 + ni * 16 + fr][kk + fq * 8];
            #pragma unroll
            for (int mi = 0; mi < 4; mi++)
                #pragma unroll
                for (int ni = 0; ni < 4; ni++)
                    acc[mi][ni] = __builtin_amdgcn_mfma_f32_16x16x32_bf16(af[mi], bfv[ni], acc[mi][ni], 0, 0, 0);
        }
    }
    float* dst = (s == 1) ? (ws + OFF_X2 + (size_t)lb * MD * 1024)
                          : (ws + OFF_C2P + (size_t)lb * MD * 1024);
    #pragma unroll
    for (int mi = 0; mi < 4; mi++) {
        #pragma unroll
        for (int ni = 0; ni < 4; ni++) {
            int gn = ntile * 256 + wave * 64 + ni * 16 + fr;
            #pragma unroll
            for (int rr = 0; rr < 4; rr++) {
                int co = mi * 16 + fq * 4 + rr;
                dst[(size_t)co * 1024 + gn] = acc[mi][ni][rr];
            }
        }
    }
}

// ---------------- reduce conv2 partial into X2 ----------------
__global__ __launch_bounds__(256) void kc2red(float* __restrict__ ws) {
    size_t i = ((size_t)blockIdx.x * 256 + threadIdx.x) * 8;
    float4 a0 = *(float4*)(ws + OFF_X2 + i);
    float4 a1 = *(float4*)(ws + OFF_X2 + i + 4);
    const float* p = ws + OFF_C2P + i;
    float4 b0 = *(const float4*)p;
    float4 b1 = *(const float4*)(p + 4);
    a0.x += b0.x; a0.y += b0.y; a0.z += b0.z; a0.w += b0.w;
    a1.x += b1.x; a1.y += b1.y; a1.z += b1.z; a1.w += b1.w;
    *(float4*)(ws + OFF_X2 + i) = a0;
    *(float4*)(ws + OFF_X2 + i + 4) = a1;
}

// ---------------- pool 4x4 + channel softmax -> patch outputs ----------------
__global__ __launch_bounds__(256) void kpool(const float* __restrict__ ws, float* __restrict__ out) {
    int lb = blockIdx.x;
    int t = threadIdx.x;
    int gy = t >> 4, gx = t & 15;
    const float* r3 = ws + OFF_RAW3 + (size_t)lb * 2 * 4096;
    float pl[2];
    #pragma unroll
    for (int ch = 0; ch < 2; ch++) {
        const float* basep = r3 + ch * 4096;
        float s = 0.f;
        #pragma unroll
        for (int dy = 0; dy < 4; dy++)
            #pragma unroll
            for (int dx = 0; dx < 4; dx++)
                s += basep[(gy * 4 + dy) * 64 + gx * 4 + dx];
        pl[ch] = s * (1.f / 16.f);
    }
    out[O_PLG + lb * NNQ + t] = pl[1] - pl[0];
    out[O_PSC + lb * NNQ + t] = 1.f / (1.f + expf(pl[0] - pl[1]));
}

// ---------------- bilinear resize 64x64 -> 240x240 (half-pixel, clamped) -------------
__global__ __launch_bounds__(256) void kresize(const float* __restrict__ ws, float* __restrict__ out) {
    int id = blockIdx.x * 256 + threadIdx.x;
    int ox = id % IMGSZ;
    int tmp = id / IMGSZ;
    int oy = tmp % IMGSZ;
    int tmp2 = tmp / IMGSZ;
    int ch = tmp2 & 1;
    int lb = tmp2 >> 1;
    const float S = 64.f / 240.f;
    float xs = fminf(fmaxf((ox + 0.5f) * S - 0.5f, 0.f), 63.f);
    float ys = fminf(fmaxf((oy + 0.5f) * S - 0.5f, 0.f), 63.f);
    int x0 = (int)xs, y0 = (int)ys;
    float fx = xs - x0, fy = ys - y0;
    int x1 = min(x0 + 1, 63), y1 = min(y0 + 1, 63);
    const float* basep = ws + OFF_RAW3 + (size_t)(lb * 2 + ch) * 4096;
    float v00 = basep[y0 * 64 + x0], v01 = basep[y0 * 64 + x1];
    float v10 = basep[y1 * 64 + x0], v11 = basep[y1 * 64 + x1];
    float v = (1.f - fy) * ((1.f - fx) * v00 + fx * v01) + fy * ((1.f - fx) * v10 + fx * v11);
    out[O_LOC + id] = v;
}

// ---------------- GAP/GMP pooled vector (many-block, coalesced) ----------------
__global__ __launch_bounds__(256) void kgap(float* __restrict__ ws,
                                            const float* __restrict__ pool_logits) {
    int bid = blockIdx.x;
    int dchunk = bid % 12;
    int lb = bid / 12;
    int l = lb >> 4;
    int t = threadIdx.x;
    int r = t >> 2, p = t & 3;
    int d = dchunk * 64 + r;
    const float* row = ws + OFF_CMAP + (size_t)lb * DD * NNQ + (size_t)d * NNQ + p * 64;
    float s = 0.f, mx = -1e30f, mn = 1e30f;
    #pragma unroll
    for (int i = 0; i < 16; i++) {
        float4 v = *(const float4*)(row + i * 4);
        s += v.x + v.y + v.z + v.w;
        mx = fmaxf(mx, fmaxf(fmaxf(v.x, v.y), fmaxf(v.z, v.w)));
        mn = fminf(mn, fminf(fminf(v.x, v.y), fminf(v.z, v.w)));
    }
    s += __shfl_xor(s, 1, 64); s += __shfl_xor(s, 2, 64);
    mx = fmaxf(mx, __shfl_xor(mx, 1, 64)); mx = fmaxf(mx, __shfl_xor(mx, 2, 64));
    mn = fminf(mn, __shfl_xor(mn, 1, 64)); mn = fminf(mn, __shfl_xor(mn, 2, 64));
    if (p == 0) {
        float p0 = pool_logits[l * 2], p1 = pool_logits[l * 2 + 1];
        float mxp = fmaxf(p0, p1);
        float e0 = expf(p0 - mxp), e1 = expf(p1 - mxp);
        float pw0 = e0 / (e0 + e1), pw1 = e1 / (e0 + e1);
        const float* bns = ws + OFF_BNSH + l * DD;
        const float* bnb = ws + OFF_BNSH + LLY * DD + l * DD;
        float scv = bns[d], bov = bnb[d];
        float gap = scv * (s * (1.f / NNQ)) + bov;
        float gmp = (scv >= 0.f) ? (scv * mx + bov) : (scv * mn + bov);
        ws[OFF_PGL + lb * DD + d] = pw0 * gap + pw1 * gmp;
    }
}

// ---------------- global head tail: MLP + LN from pooled ----------------
__global__ __launch_bounds__(256) void kglob2(const float* __restrict__ ws,
                                              const float* __restrict__ pool_logits,
                                              const float* __restrict__ mw1,
                                              const float* __restrict__ mlng,
                                              const float* __restrict__ mlnb,
                                              const float* __restrict__ mw2,
                                              const float* __restrict__ mb2,
                                              float* __restrict__ out) {
    __shared__ float pooled[DD];
    __shared__ float zbuf[HH];
    __shared__ float hbuf[HH];
    __shared__ float sm[4];
    int lb = blockIdx.x;
    int l = lb >> 4;
    int b = lb & 15;
    int t = threadIdx.x;
    float p0 = pool_logits[l * 2], p1 = pool_logits[l * 2 + 1];
    float mx = fmaxf(p0, p1);
    float e0 = expf(p0 - mx), e1 = expf(p1 - mx);
    float pw0 = e0 / (e0 + e1), pw1 = e1 / (e0 + e1);
    if (b == 0 && t < 2) out[O_PW + l * 2 + t] = (t == 0) ? pw0 : pw1;

    for (int d = t; d < DD; d += 256) pooled[d] = ws[OFF_PGL + lb * DD + d];
    __syncthreads();
    if (t < HH) {
        const float* wrow = mw1 + (size_t)(l * HH + t) * DD;
        float a = 0.f;
        for (int d2 = 0; d2 < DD; d2++) a += pooled[d2] * wrow[d2];
        zbuf[t] = a;
    }
    __syncthreads();
    float zv = (t < HH) ? zbuf[t] : 0.f;
    float s1r = blockReduceSum(zv, sm);
    float s2r = blockReduceSum(zv * zv, sm);
    float mean = s1r * (1.f / HH);
    float var = s2r * (1.f / HH) - mean * mean;
    float rstd = rsqrtf(var + 1e-5f);
    if (t < HH) {
        float h = (zbuf[t] - mean) * rstd * mlng[l * HH + t] + mlnb[l * HH + t];
        hbuf[t] = fmaxf(h, 0.f);
    }
    __syncthreads();
    float hv = (t < HH) ? hbuf[t] : 0.f;
    float w0v = (t < HH) ? mw2[(size_t)(l * 2 + 0) * HH + t] : 0.f;
    float w1v = (t < HH) ? mw2[(size_t)(l * 2 + 1) * HH + t] : 0.f;
    float s0 = blockReduceSum(hv * w0v, sm);
    float s1 = blockReduceSum(hv * w1v, sm);
    if (t == 0) out[O_GLG + lb] = (s1 + mb2[l * 2 + 1]) - (s0 + mb2[l * 2]);
}

extern "C" void kernel_launch(void* const* d_in, const int* in_sizes, int n_in,
                              void* d_out, int out_size, void* d_ws, size_t ws_size,
                              hipStream_t stream) {
    const float* query      = (const float*)d_in[0];
    const float* prompt     = (const float*)d_in[1];
    const float* sharebn_g  = (const float*)d_in[2];
    const float* sharebn_b  = (const float*)d_in[3];
    const float* lw1        = (const float*)d_in[4];
    const float* lbn1g      = (const float*)d_in[5];
    const float* lbn1b      = (const float*)d_in[6];
    const float* lwt1       = (const float*)d_in[7];
    const float* lbt1       = (const float*)d_in[8];
    const float* lw2        = (const float*)d_in[9];
    const float* lbn2g      = (const float*)d_in[10];
    const float* lbn2b      = (const float*)d_in[11];
    const float* lwt2       = (const float*)d_in[12];
    const float* lbt2       = (const float*)d_in[13];
    const float* lw3        = (const float*)d_in[14];
    const float* lb3        = (const float*)d_in[15];
    const float* pool_logits= (const float*)d_in[16];
    const float* mw1        = (const float*)d_in[17];
    const float* mlng       = (const float*)d_in[18];
    const float* mlnb       = (const float*)d_in[19];
    const float* mw2        = (const float*)d_in[20];
    const float* mb2        = (const float*)d_in[21];
    float* out = (float*)d_out;
    float* ws = (float*)d_ws;

    hipLaunchKernelGGL(knormq, dim3(LLY*BB*NNQ), dim3(192), 0, stream, query, ws);
    hipLaunchKernelGGL(ksimm, dim3(LBTOT*16), dim3(512), 0, stream, prompt, ws);
    hipLaunchKernelGGL(kpost, dim3(LBTOT*16), dim3(256), 0, stream, query, prompt, ws, out);
    hipLaunchKernelGGL(kbnstats, dim3(LLY*DD), dim3(256), 0, stream,
                       ws + OFF_CMAP, DD, NNQ, sharebn_g, sharebn_b, ws + OFF_BNSH);
    // conv1 via MFMA, split-K x6
    hipLaunchKernelGGL(kw1cvt, dim3(LLY*HH), dim3(256), 0, stream, lw1, ws);
    hipLaunchKernelGGL(kbn1cvt, dim3(LBTOT*48), dim3(256), 0, stream, ws);
    hipLaunchKernelGGL(kconv1m, dim3(LBTOT*12), dim3(256), 0, stream, ws);
    hipLaunchKernelGGL(kc1red, dim3(768), dim3(256), 0, stream, ws);
    hipLaunchKernelGGL(kbnstats, dim3(LLY*HH), dim3(256), 0, stream,
                       ws + OFF_X1, HH, 256, lbn1g, lbn1b, ws + OFF_BN1);
    // convT1 via MFMA
    hipLaunchKernelGGL(kxcvt, dim3(LBTOT*8), dim3(256), 0, stream,
                       ws + OFF_X1, ws + OFF_BN1, (unsigned short*)(ws + OFF_T2) + X1B_SH,
                       HH, 256, 4, 2);
    hipLaunchKernelGGL(kwtcvt, dim3(LLY*HH), dim3(128), 0, stream,
                       lwt1, (unsigned short*)(ws + OFF_T2) + WT1B_SH, HH, HH);
    hipLaunchKernelGGL(kconvTm, dim3(LBTOT*4*2), dim3(256), 0, stream,
                       (const unsigned short*)(ws + OFF_T2) + X1B_SH,
                       (const unsigned short*)(ws + OFF_T2) + WT1B_SH,
                       lbt1, ws + OFF_T1, HH, HH, 4, 1, 2);
    // conv2 via MFMA, split-K x2
    hipLaunchKernelGGL(kt1cvt, dim3(LBTOT*32), dim3(256), 0, stream, ws);
    hipLaunchKernelGGL(kw2cvt, dim3(LLY*MD), dim3(256), 0, stream, lw2, ws);
    hipLaunchKernelGGL(kconv2m, dim3(LBTOT*8), dim3(256), 0, stream, ws);
    hipLaunchKernelGGL(kc2red, dim3(1536), dim3(256), 0, stream, ws);
    hipLaunchKernelGGL(kbnstats, dim3(LLY*MD), dim3(256), 0, stream,
                       ws + OFF_X2, MD, 1024, lbn2g, lbn2b, ws + OFF_BN2);
    // convT2 + fused conv3 -> RAW3 (no T2 tensor)
    hipLaunchKernelGGL(kxcvt, dim3(LBTOT*16), dim3(256), 0, stream,
                       ws + OFF_X2, ws + OFF_BN2, (unsigned short*)(ws + OFF_X1),
                       MD, 1024, 16, 1);
    hipLaunchKernelGGL(kwtcvt, dim3(LLY*MD), dim3(128), 0, stream,
                       lwt2, (unsigned short*)(ws + OFF_X2), MD, MD);
    hipLaunchKernelGGL(kconvT2f, dim3(LBTOT*4*4), dim3(256), 0, stream,
                       (const unsigned short*)(ws + OFF_X1),
                       (const unsigned short*)(ws + OFF_X2),
                       lbt2, lw3, lb3, ws);
    hipLaunchKernelGGL(kpool, dim3(LBTOT), dim3(256), 0, stream, ws, out);
    hipLaunchKernelGGL(kresize, dim3(LLY*BB*2*IMGSZ*IMGSZ/256), dim3(256), 0, stream, ws, out);
    hipLaunchKernelGGL(kgap, dim3(LBTOT*12), dim3(256), 0, stream, ws, pool_logits);
    hipLaunchKernelGGL(kglob2, dim3(LBTOT), dim3(256), 0, stream,
                       ws, pool_logits, mw1, mlng, mlnb, mw2, mb2, out);
}